// Round 1
// baseline (9818.233 us; speedup 1.0000x reference)
//
#include <hip/hip_runtime.h>
#include <math.h>

// DecoderTreeLSTM: level-parallel tree evaluation.
// N=1024 nodes, BATCH=8 roots, X_DIM=2248, HID=1024, 5*HID=5120, NC=151, EMBED=200.
// Phase A (per level): GEMM [M x 2248] @ [2248 x 6144] (+ [M x 1024] @ [1024 x 5120])
// Phase B (per node): gates -> c,h,h_final -> dist (1024x151 matvec) -> argmax -> commit.
// Grid-wide sync via monotonic atomic barrier; 512 blocks of 256 thr guaranteed co-resident
// (LDS 21.5KB -> >=7 blocks/CU capacity, launch_bounds(256,2)).

#define NBLK 512
#define NTHR 256

#define N_NODES   1024
#define OUT_DIST_FLOATS (1016 * 151)   // 153416
#define OUT_COMMIT_OFF  OUT_DIST_FLOATS

__device__ float g_h[1024 * 1024];
__device__ float g_c[1024 * 1024];
__device__ float g_buf[1024 * 6144];   // per node: [0,1024)=proj_x, [1024,6144)=g
__device__ int   g_commit[1024];
__device__ int   g_lvl_start[1025];
__device__ int   g_order[1024];
__device__ int   g_numlvl;
__device__ unsigned int g_barcnt;

__device__ __forceinline__ void gbar(unsigned int* gen) {
  __syncthreads();
  if (threadIdx.x == 0) {
    ++(*gen);
    __threadfence();  // agent-scope acq_rel fence: publish this block's stores
    __hip_atomic_fetch_add(&g_barcnt, 1u, __ATOMIC_RELEASE, __HIP_MEMORY_SCOPE_AGENT);
    const unsigned int target = (unsigned int)NBLK * (*gen);
    while (__hip_atomic_load(&g_barcnt, __ATOMIC_ACQUIRE, __HIP_MEMORY_SCOPE_AGENT) < target) {
      __builtin_amdgcn_s_sleep(2);
    }
  }
  __syncthreads();
}

// ---------------------------------------------------------------------------
// Prep: compute level of each node, bucket nodes by level, reset barrier.
// ---------------------------------------------------------------------------
__global__ void prep_kernel(const int* __restrict__ parent, float* __restrict__ out) {
  __shared__ int lvl[1024];
  __shared__ int cnt[1024];
  __shared__ int changed;
  const int i = threadIdx.x;
  const int p = parent[i];
  lvl[i] = (p < 0) ? 0 : -1;
  for (;;) {
    if (i == 0) changed = 0;
    __syncthreads();
    if (lvl[i] < 0 && lvl[p] >= 0) { lvl[i] = lvl[p] + 1; changed = 1; }
    __syncthreads();
    const int ch = changed;
    __syncthreads();
    if (ch == 0) break;
  }
  cnt[i] = 0;
  __syncthreads();
  atomicAdd(&cnt[lvl[i]], 1);
  __syncthreads();
  if (i == 0) {
    int acc = 0, nl = 0;
    for (int l = 0; l < 1024; ++l) {
      g_lvl_start[l] = acc;
      if (cnt[l] > 0) nl = l + 1;
      acc += cnt[l];
    }
    g_lvl_start[1024] = acc;
    g_numlvl = nl;
    g_barcnt = 0u;
  }
  __syncthreads();
  cnt[i] = 0;
  __syncthreads();
  const int pos = g_lvl_start[lvl[i]] + atomicAdd(&cnt[lvl[i]], 1);
  g_order[pos] = i;
  if (i < 8) out[OUT_COMMIT_OFF + 1016 + i] = 0.0f;  // trailing zeros of commitments
}

// ---------------------------------------------------------------------------
// Main persistent kernel
// ---------------------------------------------------------------------------
#define FMA4(A, S, B) do { (A).x += (S)*(B).x; (A).y += (S)*(B).y; (A).z += (S)*(B).z; (A).w += (S)*(B).w; } while(0)

__global__ __launch_bounds__(NTHR, 2) void lstm_main(
    const float* __restrict__ feat, const int* __restrict__ parent,
    const float* __restrict__ Wpx, const float* __restrict__ bpx,
    const float* __restrict__ Wix, const float* __restrict__ bix,
    const float* __restrict__ Wih, const float* __restrict__ bih,
    const float* __restrict__ Wout, const float* __restrict__ bout,
    const float* __restrict__ emb, float* __restrict__ out)
{
  // Phase A LDS: xs[32 m][36 pad] (1152 fl) + ws[32 k][132 pad] (4224 fl) = 5376 floats
  __shared__ float smem[5376];
  unsigned int gen = 0;
  const int tid = threadIdx.x;
  const int nl = g_numlvl;

  // phase-A thread roles
  const int mi_s = tid >> 3, kq = tid & 7;   // xs staging: m-row, k-quad
  const int kk_s = tid >> 3, nq = tid & 7;   // ws staging: k-row, n-16-group
  const int mg = tid >> 5, ng = tid & 31;    // compute: 4m group (0..7), 4n group (0..31)

  for (int L = 0; L < nl; ++L) {
    const int s0 = g_lvl_start[L];
    const int M  = g_lvl_start[L + 1] - s0;

    // ---------------- Phase A: proj_x and g for all nodes of this level ----
    const int nmt = (M + 31) >> 5;
    const int ntile = nmt * 48;               // 48 column tiles of 128 over 6144
    for (int t = (int)blockIdx.x; t < ntile; t += NBLK) {
      const int mt = t / 48, ct = t % 48;
      const int cg0 = ct << 7;                // global output column base (0..6143)
      const bool isproj = (cg0 < 1024);

      const int mrow = mt * 32 + mi_s;
      const int node_s = (mrow < M) ? g_order[s0 + mrow] : -1;
      const int p_s = (node_s >= 0) ? parent[node_s] : 0;
      const float* xsrc_f = (node_s >= 0) ? (feat + (size_t)node_s * 2048) : (const float*)0;
      const int erow = (node_s >= 0) ? ((p_s < 0) ? 0 : g_commit[p_s]) : 0;
      const float* hb = (node_s >= 0 && p_s >= 0) ? (g_h + (size_t)p_s * 1024) : (const float*)0;

      const float* W1 = isproj ? Wpx : Wix;
      const int Ncols = isproj ? 1024 : 5120;
      const int c0 = isproj ? cg0 : (cg0 - 1024);

      float4 acc[4];
      acc[0] = make_float4(0.f, 0.f, 0.f, 0.f);
      acc[1] = acc[0]; acc[2] = acc[0]; acc[3] = acc[0];

      const int nchunks = isproj ? 71 : 103;  // 71 x-chunks (+32 h-chunks for g tiles)
      for (int kc = 0; kc < nchunks; ++kc) {
        float4 xv = make_float4(0.f, 0.f, 0.f, 0.f);
        const float* wbase = (const float*)0;
        if (kc < 71) {
          const int k0 = kc << 5;
          const int k = k0 + (kq << 2);
          if (node_s >= 0) {
            if (k0 < 2048) {
              xv = *(const float4*)(xsrc_f + k);
            } else {
              const int ke = k - 2048;
              if (ke <= 196) xv = *(const float4*)(emb + (size_t)erow * 200 + ke);
            }
          }
          const int kr = k0 + kk_s;
          if (kr < 2248) wbase = W1 + (size_t)kr * Ncols + c0 + (nq << 4);
        } else {
          const int k0 = (kc - 71) << 5;
          if (hb) xv = *(const float4*)(hb + k0 + (kq << 2));
          const int kr = k0 + kk_s;  // always < 1024
          wbase = Wih + (size_t)kr * 5120 + c0 + (nq << 4);
        }
        *(float4*)(smem + mi_s * 36 + (kq << 2)) = xv;
        float4 w0 = make_float4(0.f,0.f,0.f,0.f), w1 = w0, w2 = w0, w3 = w0;
        if (wbase) {
          w0 = *(const float4*)(wbase + 0);
          w1 = *(const float4*)(wbase + 4);
          w2 = *(const float4*)(wbase + 8);
          w3 = *(const float4*)(wbase + 12);
        }
        float* wrow = smem + 1152 + kk_s * 132 + (nq << 4);
        *(float4*)(wrow + 0) = w0; *(float4*)(wrow + 4) = w1;
        *(float4*)(wrow + 8) = w2; *(float4*)(wrow + 12) = w3;
        __syncthreads();

        const float4* xs4 = (const float4*)smem;            // row stride 9 float4
        const float4* ws4 = (const float4*)(smem + 1152);   // row stride 33 float4
        #pragma unroll
        for (int kk = 0; kk < 32; kk += 4) {
          const int kq4 = kk >> 2;
          const float4 a0 = xs4[(4 * mg + 0) * 9 + kq4];
          const float4 a1 = xs4[(4 * mg + 1) * 9 + kq4];
          const float4 a2 = xs4[(4 * mg + 2) * 9 + kq4];
          const float4 a3 = xs4[(4 * mg + 3) * 9 + kq4];
          const float4 b0 = ws4[(kk + 0) * 33 + ng];
          const float4 b1 = ws4[(kk + 1) * 33 + ng];
          const float4 b2 = ws4[(kk + 2) * 33 + ng];
          const float4 b3 = ws4[(kk + 3) * 33 + ng];
          FMA4(acc[0], a0.x, b0); FMA4(acc[0], a0.y, b1); FMA4(acc[0], a0.z, b2); FMA4(acc[0], a0.w, b3);
          FMA4(acc[1], a1.x, b0); FMA4(acc[1], a1.y, b1); FMA4(acc[1], a1.z, b2); FMA4(acc[1], a1.w, b3);
          FMA4(acc[2], a2.x, b0); FMA4(acc[2], a2.y, b1); FMA4(acc[2], a2.z, b2); FMA4(acc[2], a2.w, b3);
          FMA4(acc[3], a3.x, b0); FMA4(acc[3], a3.y, b1); FMA4(acc[3], a3.z, b2); FMA4(acc[3], a3.w, b3);
        }
        __syncthreads();
      }

      // bias + store
      float4 bias;
      if (isproj) {
        bias = *(const float4*)(bpx + cg0 + (ng << 2));
      } else {
        const float4 bb1 = *(const float4*)(bix + c0 + (ng << 2));
        const float4 bb2 = *(const float4*)(bih + c0 + (ng << 2));
        bias = make_float4(bb1.x + bb2.x, bb1.y + bb2.y, bb1.z + bb2.z, bb1.w + bb2.w);
      }
      #pragma unroll
      for (int i = 0; i < 4; ++i) {
        const int m = mt * 32 + mg * 4 + i;
        if (m < M) {
          const int nd = g_order[s0 + m];
          float4 o = make_float4(acc[i].x + bias.x, acc[i].y + bias.y,
                                 acc[i].z + bias.z, acc[i].w + bias.w);
          *(float4*)(g_buf + (size_t)nd * 6144 + cg0 + (ng << 2)) = o;
        }
      }
    }
    gbar(&gen);

    // ---------------- Phase B: gates, c/h/h_final, dist, argmax, commit ----
    for (int ni = (int)blockIdx.x; ni < M; ni += NBLK) {
      const int node = g_order[s0 + ni];
      const int p = parent[node];
      const float* gb = g_buf + (size_t)node * 6144;
      for (int j = tid; j < 1024; j += NTHR) {
        const float proj = gb[j];
        const float vi = gb[1024 + j];
        const float vo = gb[2048 + j];
        const float vf = gb[3072 + j];
        const float vu = gb[4096 + j];
        const float vr = gb[5120 + j];
        const float ig = 1.f / (1.f + expf(-vi));
        const float og = 1.f / (1.f + expf(-vo));
        const float fg = 1.f / (1.f + expf(-vf));
        const float rg = 1.f / (1.f + expf(-vr));
        const float ug = tanhf(vu);
        const float pc = (p >= 0) ? g_c[(size_t)p * 1024 + j] : 0.f;
        const float c = ig * ug + fg * pc;
        const float h = og * tanhf(c);
        const float hf = rg * h + (1.f - rg) * proj;
        g_c[(size_t)node * 1024 + j] = c;
        g_h[(size_t)node * 1024 + j] = hf;
        smem[j] = hf;   // hsh
      }
      __syncthreads();
      {
        const int w = tid >> 6, lane = tid & 63;
        const int kbeg = w << 8;
        float* part = smem + 1024;  // [4][152]
        for (int cb = 0; cb < 192; cb += 64) {
          const int col = cb + lane;
          if (col < 151) {
            float a0 = 0.f, a1 = 0.f, a2 = 0.f, a3 = 0.f;
            const float* wp = Wout + (size_t)kbeg * 151 + col;
            const float* hp = smem + kbeg;
            for (int kk = 0; kk < 256; kk += 4) {
              a0 += hp[kk + 0] * wp[(size_t)(kk + 0) * 151];
              a1 += hp[kk + 1] * wp[(size_t)(kk + 1) * 151];
              a2 += hp[kk + 2] * wp[(size_t)(kk + 2) * 151];
              a3 += hp[kk + 3] * wp[(size_t)(kk + 3) * 151];
            }
            part[w * 152 + col] = (a0 + a1) + (a2 + a3);
          }
        }
      }
      __syncthreads();
      if (tid < 151) {
        const float* part = smem + 1024;
        const float d = part[tid] + part[152 + tid] + part[304 + tid] + part[456 + tid] + bout[tid];
        smem[1632 + tid] = d;
        if (node >= 8) out[(size_t)(node - 8) * 151 + tid] = d;
      }
      __syncthreads();
      if (tid < 64) {
        float bv = -3.4e38f; int bidx = 1;
        for (int cb = 0; cb < 192; cb += 64) {
          const int col = 1 + cb + tid;   // argmax over dist[1:] -> +1
          if (col < 151) {
            const float v = smem[1632 + col];
            if (v > bv) { bv = v; bidx = col; }
          }
        }
        for (int off = 32; off > 0; off >>= 1) {
          const float ov = __shfl_down(bv, off);
          const int oi = __shfl_down(bidx, off);
          if (ov > bv || (ov == bv && oi < bidx)) { bv = ov; bidx = oi; }
        }
        if (tid == 0) {
          g_commit[node] = bidx;
          if (node >= 8) out[OUT_COMMIT_OFF + node - 8] = (float)bidx;
        }
      }
      __syncthreads();
    }
    gbar(&gen);
  }
}

extern "C" void kernel_launch(void* const* d_in, const int* in_sizes, int n_in,
                              void* d_out, int out_size, void* d_ws, size_t ws_size,
                              hipStream_t stream) {
  const float* feat   = (const float*)d_in[0];
  const int*   parent = (const int*)d_in[1];
  // d_in[2] = batch_size (8), hardcoded
  const float* Wpx  = (const float*)d_in[3];
  const float* bpx  = (const float*)d_in[4];
  const float* Wix  = (const float*)d_in[5];
  const float* bix  = (const float*)d_in[6];
  const float* Wih  = (const float*)d_in[7];
  const float* bih  = (const float*)d_in[8];
  const float* Wout = (const float*)d_in[9];
  const float* bout = (const float*)d_in[10];
  const float* emb  = (const float*)d_in[11];
  float* out = (float*)d_out;

  hipLaunchKernelGGL(prep_kernel, dim3(1), dim3(1024), 0, stream, parent, out);
  hipLaunchKernelGGL(lstm_main, dim3(NBLK), dim3(NTHR), 0, stream,
                     feat, parent, Wpx, bpx, Wix, bix, Wih, bih, Wout, bout, emb, out);
}

// Round 2
// 9693.744 us; speedup vs baseline: 1.0128x; 1.0128x over previous
//
#include <hip/hip_runtime.h>
#include <math.h>

// DecoderTreeLSTM: level-parallel tree evaluation, round 2.
// fp32 GEMM restructured: 512-thr blocks, double-buffered global_load_lds staging,
// unified padded K layout: [0,2048)=features, [2048,2272)=embed(pad 224), [2272,3296)=parent h.
// Phase A: per level, tiles of 32 rows x 128 cols over 6144 output cols (48 col-tiles).
// Phase B: gates -> c,h,h_final -> dist -> argmax -> commit. Grid barrier between phases.

#define NBLK 512
#define NTHR 512
#define OUT_COMMIT_OFF (1016 * 151)

__device__ __align__(16) float g_h[1024 * 1024];
__device__ __align__(16) float g_c[1024 * 1024];
__device__ __align__(16) float g_buf[1024 * 6144];   // [0,1024)=proj_x, [1024,6144)=g
__device__ __align__(16) float g_embpad[152 * 224];
__device__ __align__(16) float g_zero[64];
__device__ int   g_commit[1024];
__device__ int   g_lvl_start[1025];
__device__ int   g_order[1024];
__device__ int   g_numlvl;
__device__ unsigned int g_barcnt;

__device__ __forceinline__ void gload_lds16(const float* g, float* s) {
  __builtin_amdgcn_global_load_lds(
      (const __attribute__((address_space(1))) void*)g,
      (__attribute__((address_space(3))) void*)s, 16, 0, 0);
}

__device__ __forceinline__ void gbar(unsigned int* gen) {
  __syncthreads();
  if (threadIdx.x == 0) {
    ++(*gen);
    __threadfence();
    __hip_atomic_fetch_add(&g_barcnt, 1u, __ATOMIC_RELEASE, __HIP_MEMORY_SCOPE_AGENT);
    const unsigned int target = (unsigned int)NBLK * (*gen);
    while (__hip_atomic_load(&g_barcnt, __ATOMIC_ACQUIRE, __HIP_MEMORY_SCOPE_AGENT) < target) {
      __builtin_amdgcn_s_sleep(2);
    }
  }
  __syncthreads();
}

// ---------------------------------------------------------------------------
// Prep: levels, embpad table, zero page, barrier reset, trailing output zeros.
// ---------------------------------------------------------------------------
__global__ void prep_kernel(const int* __restrict__ parent,
                            const float* __restrict__ emb,
                            float* __restrict__ out) {
  __shared__ int lvl[1024];
  __shared__ int cnt[1024];
  __shared__ int changed;
  const int i = threadIdx.x;
  const int p = parent[i];
  lvl[i] = (p < 0) ? 0 : -1;
  for (;;) {
    if (i == 0) changed = 0;
    __syncthreads();
    if (lvl[i] < 0 && lvl[p] >= 0) { lvl[i] = lvl[p] + 1; changed = 1; }
    __syncthreads();
    const int ch = changed;
    __syncthreads();
    if (ch == 0) break;
  }
  cnt[i] = 0;
  __syncthreads();
  atomicAdd(&cnt[lvl[i]], 1);
  __syncthreads();
  if (i == 0) {
    int acc = 0, nl = 0;
    for (int l = 0; l < 1024; ++l) {
      g_lvl_start[l] = acc;
      if (cnt[l] > 0) nl = l + 1;
      acc += cnt[l];
    }
    g_lvl_start[1024] = acc;
    g_numlvl = nl;
    g_barcnt = 0u;
  }
  __syncthreads();
  cnt[i] = 0;
  __syncthreads();
  const int pos = g_lvl_start[lvl[i]] + atomicAdd(&cnt[lvl[i]], 1);
  g_order[pos] = i;
  // embpad [152][224] (zero-padded copy of embed_table [152][200])
  for (int j = i; j < 152 * 224; j += 1024) {
    const int r = j / 224, cc = j - r * 224;
    g_embpad[j] = (cc < 200) ? emb[r * 200 + cc] : 0.0f;
  }
  if (i < 64) g_zero[i] = 0.0f;
  if (i < 8) out[OUT_COMMIT_OFF + 1016 + i] = 0.0f;
}

// ---------------------------------------------------------------------------
// Main persistent kernel
// ---------------------------------------------------------------------------
#define STEP(ACC, AV)                                  \
  ACC.x += AV.x * b0.x; ACC.y += AV.x * b0.y;          \
  ACC.x += AV.y * b1.x; ACC.y += AV.y * b1.y;          \
  ACC.x += AV.z * b2.x; ACC.y += AV.z * b2.y;          \
  ACC.x += AV.w * b3.x; ACC.y += AV.w * b3.y;

__global__ __launch_bounds__(NTHR, 4) void lstm_main(
    const float* __restrict__ feat, const int* __restrict__ parent,
    const float* __restrict__ Wpx, const float* __restrict__ bpx,
    const float* __restrict__ Wix, const float* __restrict__ bix,
    const float* __restrict__ Wih, const float* __restrict__ bih,
    const float* __restrict__ Wout, const float* __restrict__ bout,
    float* __restrict__ out)
{
  // smem: [0,2048) = A double buffer (2 x 32m x 32k), [2048,10240) = B dbuf (2 x 32k x 128n)
  __shared__ __align__(16) float smem[10240];
  __shared__ int s_node[32], s_erow[32], s_ppar[32];
  unsigned int gen = 0;
  const int tid = threadIdx.x;
  const int w = tid >> 6, l = tid & 63;
  const int nl = g_numlvl;

  for (int L = 0; L < nl; ++L) {
    const int s0 = g_lvl_start[L];
    const int M  = g_lvl_start[L + 1] - s0;
    const int nmt = (M + 31) >> 5;
    const int ntile = nmt * 48;

    // ---------------- Phase A ----------------
    for (int t = (int)blockIdx.x; t < ntile; t += NBLK) {
      const int mt = t / 48, ct = t - (t / 48) * 48;
      const int c0 = ct << 7;
      const bool isproj = (c0 < 1024);
      const float* W1 = isproj ? Wpx : Wix;
      const int N1 = isproj ? 1024 : 5120;
      const int c0x = isproj ? c0 : (c0 - 1024);
      const int nch = isproj ? 71 : 103;

      __syncthreads();   // protect smem/meta reuse
      if (tid < 32) {
        const int m = (mt << 5) + tid;
        int nd = -1, er = 0, pp = -1;
        if (m < M) { nd = g_order[s0 + m]; pp = parent[nd]; er = (pp < 0) ? 0 : g_commit[pp]; }
        s_node[tid] = nd; s_erow[tid] = er; s_ppar[tid] = pp;
      }
      __syncthreads();

      auto STAGE = [&](int c, int buf) {
        const int kb = c << 5;
        if (w < 4) {  // A tile: 32m x 32k = 4KB, waves 0-3, 1 issue each
          const int mA = (w << 3) + (l >> 3);
          const int k = kb + ((l & 7) << 2);
          const int nd = s_node[mA];
          const float* src;
          if (nd < 0) src = g_zero;
          else if (kb < 2048) src = feat + ((size_t)nd << 11) + k;
          else if (kb < 2272) src = g_embpad + s_erow[mA] * 224 + (k - 2048);
          else {
            const int pp = s_ppar[mA];
            src = (pp >= 0) ? (g_h + ((size_t)pp << 10) + (k - 2272)) : g_zero;
          }
          gload_lds16(src, smem + buf * 1024 + (w << 8));
        }
        // B tile: 32k x 128n = 16KB, all 8 waves, 2 issues each (2 rows per issue)
        #pragma unroll
        for (int j = 0; j < 2; ++j) {
          const int row = (w << 2) + (j << 1) + (l >> 5);
          const int colq = (l & 31) << 2;
          const float* src;
          if (kb < 2272) {
            const int r = kb + row;
            src = (r < 2248) ? (W1 + (size_t)r * N1 + c0x + colq) : g_zero;
          } else {
            src = Wih + (size_t)(kb - 2272 + row) * 5120 + c0x + colq;
          }
          gload_lds16(src, smem + 2048 + buf * 4096 + (((w << 2) + (j << 1)) << 7));
        }
      };

      float2 acc0 = {0.f, 0.f}, acc1 = {0.f, 0.f}, acc2 = {0.f, 0.f}, acc3 = {0.f, 0.f};
      STAGE(0, 0);
      asm volatile("s_waitcnt vmcnt(0)" ::: "memory");
      __syncthreads();
      for (int c = 0; c < nch; ++c) {
        const int cur = c & 1;
        if (c + 1 < nch) STAGE(c + 1, cur ^ 1);
        const float* Abuf = smem + cur * 1024 + (w << 7);   // this wave's 4 m-rows
        const float* Bbuf = smem + 2048 + cur * 4096;
        #pragma unroll
        for (int kq = 0; kq < 8; ++kq) {
          const float4 a0 = *(const float4*)(Abuf + 0 * 32 + (kq << 2));
          const float4 a1 = *(const float4*)(Abuf + 1 * 32 + (kq << 2));
          const float4 a2 = *(const float4*)(Abuf + 2 * 32 + (kq << 2));
          const float4 a3 = *(const float4*)(Abuf + 3 * 32 + (kq << 2));
          const float2 b0 = *(const float2*)(Bbuf + ((kq << 2) + 0) * 128 + (l << 1));
          const float2 b1 = *(const float2*)(Bbuf + ((kq << 2) + 1) * 128 + (l << 1));
          const float2 b2 = *(const float2*)(Bbuf + ((kq << 2) + 2) * 128 + (l << 1));
          const float2 b3 = *(const float2*)(Bbuf + ((kq << 2) + 3) * 128 + (l << 1));
          STEP(acc0, a0) STEP(acc1, a1) STEP(acc2, a2) STEP(acc3, a3)
        }
        asm volatile("s_waitcnt vmcnt(0)" ::: "memory");
        __syncthreads();
      }

      // bias + writeback
      const int cc = c0 + (l << 1);
      float2 bias;
      if (isproj) { bias.x = bpx[cc]; bias.y = bpx[cc + 1]; }
      else {
        bias.x = bix[cc - 1024] + bih[cc - 1024];
        bias.y = bix[cc - 1023] + bih[cc - 1023];
      }
      float2 r0 = acc0, r1 = acc1, r2 = acc2, r3 = acc3;
      {
        const int nd0 = s_node[(w << 2) + 0];
        const int nd1 = s_node[(w << 2) + 1];
        const int nd2 = s_node[(w << 2) + 2];
        const int nd3 = s_node[(w << 2) + 3];
        if (nd0 >= 0) { float2 o; o.x = r0.x + bias.x; o.y = r0.y + bias.y; *(float2*)(g_buf + (size_t)nd0 * 6144 + cc) = o; }
        if (nd1 >= 0) { float2 o; o.x = r1.x + bias.x; o.y = r1.y + bias.y; *(float2*)(g_buf + (size_t)nd1 * 6144 + cc) = o; }
        if (nd2 >= 0) { float2 o; o.x = r2.x + bias.x; o.y = r2.y + bias.y; *(float2*)(g_buf + (size_t)nd2 * 6144 + cc) = o; }
        if (nd3 >= 0) { float2 o; o.x = r3.x + bias.x; o.y = r3.y + bias.y; *(float2*)(g_buf + (size_t)nd3 * 6144 + cc) = o; }
      }
    }
    gbar(&gen);

    // ---------------- Phase B ----------------
    for (int ni = (int)blockIdx.x; ni < M; ni += NBLK) {
      const int node = g_order[s0 + ni];
      const int p = parent[node];
      const float* gb = g_buf + (size_t)node * 6144;
      for (int j = tid; j < 1024; j += NTHR) {
        const float proj = gb[j];
        const float vi = gb[1024 + j];
        const float vo = gb[2048 + j];
        const float vf = gb[3072 + j];
        const float vu = gb[4096 + j];
        const float vr = gb[5120 + j];
        const float ig = 1.f / (1.f + expf(-vi));
        const float og = 1.f / (1.f + expf(-vo));
        const float fg = 1.f / (1.f + expf(-vf));
        const float rg = 1.f / (1.f + expf(-vr));
        const float ug = tanhf(vu);
        const float pc = (p >= 0) ? g_c[(size_t)p * 1024 + j] : 0.f;
        const float c = ig * ug + fg * pc;
        const float h = og * tanhf(c);
        const float hf = rg * h + (1.f - rg) * proj;
        g_c[(size_t)node * 1024 + j] = c;
        g_h[(size_t)node * 1024 + j] = hf;
        smem[j] = hf;
      }
      __syncthreads();
      {
        const int kbeg = w << 7;   // 8 waves x 128 k
        for (int cb = 0; cb < 192; cb += 64) {
          const int col = cb + l;
          if (col < 151) {
            float a0 = 0.f, a1 = 0.f, a2 = 0.f, a3 = 0.f;
            const float* wp = Wout + (size_t)kbeg * 151 + col;
            const float* hp = smem + kbeg;
            for (int kk = 0; kk < 128; kk += 4) {
              a0 += hp[kk + 0] * wp[(size_t)(kk + 0) * 151];
              a1 += hp[kk + 1] * wp[(size_t)(kk + 1) * 151];
              a2 += hp[kk + 2] * wp[(size_t)(kk + 2) * 151];
              a3 += hp[kk + 3] * wp[(size_t)(kk + 3) * 151];
            }
            smem[1024 + w * 152 + col] = (a0 + a1) + (a2 + a3);
          }
        }
      }
      __syncthreads();
      if (tid < 151) {
        float d = bout[tid];
        #pragma unroll
        for (int ww = 0; ww < 8; ++ww) d += smem[1024 + ww * 152 + tid];
        smem[2400 + tid] = d;
        if (node >= 8) out[(size_t)(node - 8) * 151 + tid] = d;
      }
      __syncthreads();
      if (tid < 64) {
        float bv = -3.4e38f; int bidx = 1;
        for (int cb = 0; cb < 192; cb += 64) {
          const int col = 1 + cb + tid;
          if (col < 151) {
            const float v = smem[2400 + col];
            if (v > bv) { bv = v; bidx = col; }
          }
        }
        for (int off = 32; off > 0; off >>= 1) {
          const float ov = __shfl_down(bv, off);
          const int oi = __shfl_down(bidx, off);
          if (ov > bv || (ov == bv && oi < bidx)) { bv = ov; bidx = oi; }
        }
        if (tid == 0) {
          g_commit[node] = bidx;
          if (node >= 8) out[OUT_COMMIT_OFF + node - 8] = (float)bidx;
        }
      }
      __syncthreads();
    }
    gbar(&gen);
  }
}

extern "C" void kernel_launch(void* const* d_in, const int* in_sizes, int n_in,
                              void* d_out, int out_size, void* d_ws, size_t ws_size,
                              hipStream_t stream) {
  const float* feat   = (const float*)d_in[0];
  const int*   parent = (const int*)d_in[1];
  // d_in[2] = batch_size (8), hardcoded
  const float* Wpx  = (const float*)d_in[3];
  const float* bpx  = (const float*)d_in[4];
  const float* Wix  = (const float*)d_in[5];
  const float* bix  = (const float*)d_in[6];
  const float* Wih  = (const float*)d_in[7];
  const float* bih  = (const float*)d_in[8];
  const float* Wout = (const float*)d_in[9];
  const float* bout = (const float*)d_in[10];
  const float* emb  = (const float*)d_in[11];
  float* out = (float*)d_out;

  hipLaunchKernelGGL(prep_kernel, dim3(1), dim3(1024), 0, stream, parent, emb, out);
  hipLaunchKernelGGL(lstm_main, dim3(NBLK), dim3(NTHR), 0, stream,
                     feat, parent, Wpx, bpx, Wix, bix, Wih, bih, Wout, bout, out);
}

// Round 4
// 3328.218 us; speedup vs baseline: 2.9500x; 2.9126x over previous
//
#include <hip/hip_runtime.h>
#include <math.h>

// DecoderTreeLSTM: level-parallel tree evaluation, round 4 (R3 fence fix).
// Grid barrier: RELAXED spin + s_sleep (no buffer_inv per poll), one RELEASE
// fetch_add (single wbl2) and one acquire fence per block per barrier via
// __builtin_amdgcn_fence (this ROCm lacks __hip_atomic_fence).

#define NBLK 512
#define NTHR 512
#define OUT_COMMIT_OFF (1016 * 151)

__device__ __align__(16) float g_h[1024 * 1024];
__device__ __align__(16) float g_c[1024 * 1024];
__device__ __align__(16) float g_buf[1024 * 6144];   // [0,1024)=proj_x, [1024,6144)=g
__device__ __align__(16) float g_embpad[152 * 224];
__device__ __align__(16) float g_zero[64];
__device__ int   g_commit[1024];
__device__ int   g_lvl_start[1025];
__device__ int   g_order[1024];
__device__ int   g_numlvl;
__device__ unsigned int g_barcnt;

__device__ __forceinline__ void gload_lds16(const float* g, float* s) {
  __builtin_amdgcn_global_load_lds(
      (const __attribute__((address_space(1))) void*)g,
      (__attribute__((address_space(3))) void*)s, 16, 0, 0);
}

__device__ __forceinline__ void gbar(unsigned int* gen) {
  __syncthreads();
  if (threadIdx.x == 0) {
    ++(*gen);
    // single release: one wbl2 (block's stores already drained to L2 at s_barrier)
    __hip_atomic_fetch_add(&g_barcnt, 1u, __ATOMIC_RELEASE, __HIP_MEMORY_SCOPE_AGENT);
    const unsigned int target = (unsigned int)NBLK * (*gen);
    // RELAXED spin: no buffer_inv per poll
    while (__hip_atomic_load(&g_barcnt, __ATOMIC_RELAXED, __HIP_MEMORY_SCOPE_AGENT) < target) {
      __builtin_amdgcn_s_sleep(8);
    }
    // single acquire: one L1+L2 invalidate per block per barrier
    __builtin_amdgcn_fence(__ATOMIC_ACQUIRE, "agent");
  }
  __syncthreads();
}

// ---------------------------------------------------------------------------
// Prep: levels, embpad table, zero page, barrier reset, trailing output zeros.
// ---------------------------------------------------------------------------
__global__ void prep_kernel(const int* __restrict__ parent,
                            const float* __restrict__ emb,
                            float* __restrict__ out) {
  __shared__ int lvl[1024];
  __shared__ int cnt[1024];
  __shared__ int changed;
  const int i = threadIdx.x;
  const int p = parent[i];
  lvl[i] = (p < 0) ? 0 : -1;
  for (;;) {
    if (i == 0) changed = 0;
    __syncthreads();
    if (lvl[i] < 0 && lvl[p] >= 0) { lvl[i] = lvl[p] + 1; changed = 1; }
    __syncthreads();
    const int ch = changed;
    __syncthreads();
    if (ch == 0) break;
  }
  cnt[i] = 0;
  __syncthreads();
  atomicAdd(&cnt[lvl[i]], 1);
  __syncthreads();
  if (i == 0) {
    int acc = 0, nl = 0;
    for (int l = 0; l < 1024; ++l) {
      g_lvl_start[l] = acc;
      if (cnt[l] > 0) nl = l + 1;
      acc += cnt[l];
    }
    g_lvl_start[1024] = acc;
    g_numlvl = nl;
    g_barcnt = 0u;
  }
  __syncthreads();
  cnt[i] = 0;
  __syncthreads();
  const int pos = g_lvl_start[lvl[i]] + atomicAdd(&cnt[lvl[i]], 1);
  g_order[pos] = i;
  // embpad [152][224] (zero-padded copy of embed_table [152][200])
  for (int j = i; j < 152 * 224; j += 1024) {
    const int r = j / 224, cc = j - r * 224;
    g_embpad[j] = (cc < 200) ? emb[r * 200 + cc] : 0.0f;
  }
  if (i < 64) g_zero[i] = 0.0f;
  if (i < 8) out[OUT_COMMIT_OFF + 1016 + i] = 0.0f;
}

// ---------------------------------------------------------------------------
// Main persistent kernel
// ---------------------------------------------------------------------------
#define STEP(ACC, AV)                                  \
  ACC.x += AV.x * b0.x; ACC.y += AV.x * b0.y;          \
  ACC.x += AV.y * b1.x; ACC.y += AV.y * b1.y;          \
  ACC.x += AV.z * b2.x; ACC.y += AV.z * b2.y;          \
  ACC.x += AV.w * b3.x; ACC.y += AV.w * b3.y;

__global__ __launch_bounds__(NTHR, 4) void lstm_main(
    const float* __restrict__ feat, const int* __restrict__ parent,
    const float* __restrict__ Wpx, const float* __restrict__ bpx,
    const float* __restrict__ Wix, const float* __restrict__ bix,
    const float* __restrict__ Wih, const float* __restrict__ bih,
    const float* __restrict__ Wout, const float* __restrict__ bout,
    float* __restrict__ out)
{
  // smem: [0,2048) = A double buffer (2 x 32m x 32k), [2048,10240) = B dbuf (2 x 32k x 128n)
  __shared__ __align__(16) float smem[10240];
  __shared__ int s_node[32], s_erow[32], s_ppar[32];
  unsigned int gen = 0;
  const int tid = threadIdx.x;
  const int w = tid >> 6, l = tid & 63;
  const int nl = g_numlvl;

  for (int L = 0; L < nl; ++L) {
    const int s0 = g_lvl_start[L];
    const int M  = g_lvl_start[L + 1] - s0;
    const int nmt = (M + 31) >> 5;
    const int ntile = nmt * 48;

    // ---------------- Phase A ----------------
    for (int t = (int)blockIdx.x; t < ntile; t += NBLK) {
      const int mt = t / 48, ct = t - (t / 48) * 48;
      const int c0 = ct << 7;
      const bool isproj = (c0 < 1024);
      const float* W1 = isproj ? Wpx : Wix;
      const int N1 = isproj ? 1024 : 5120;
      const int c0x = isproj ? c0 : (c0 - 1024);
      const int nch = isproj ? 71 : 103;

      __syncthreads();   // protect smem/meta reuse
      if (tid < 32) {
        const int m = (mt << 5) + tid;
        int nd = -1, er = 0, pp = -1;
        if (m < M) { nd = g_order[s0 + m]; pp = parent[nd]; er = (pp < 0) ? 0 : g_commit[pp]; }
        s_node[tid] = nd; s_erow[tid] = er; s_ppar[tid] = pp;
      }
      __syncthreads();

      auto STAGE = [&](int c, int buf) {
        const int kb = c << 5;
        if (w < 4) {  // A tile: 32m x 32k = 4KB, waves 0-3, 1 issue each
          const int mA = (w << 3) + (l >> 3);
          const int k = kb + ((l & 7) << 2);
          const int nd = s_node[mA];
          const float* src;
          if (nd < 0) src = g_zero;
          else if (kb < 2048) src = feat + ((size_t)nd << 11) + k;
          else if (kb < 2272) src = g_embpad + s_erow[mA] * 224 + (k - 2048);
          else {
            const int pp = s_ppar[mA];
            src = (pp >= 0) ? (g_h + ((size_t)pp << 10) + (k - 2272)) : g_zero;
          }
          gload_lds16(src, smem + buf * 1024 + (w << 8));
        }
        // B tile: 32k x 128n = 16KB, all 8 waves, 2 issues each (2 rows per issue)
        #pragma unroll
        for (int j = 0; j < 2; ++j) {
          const int row = (w << 2) + (j << 1) + (l >> 5);
          const int colq = (l & 31) << 2;
          const float* src;
          if (kb < 2272) {
            const int r = kb + row;
            src = (r < 2248) ? (W1 + (size_t)r * N1 + c0x + colq) : g_zero;
          } else {
            src = Wih + (size_t)(kb - 2272 + row) * 5120 + c0x + colq;
          }
          gload_lds16(src, smem + 2048 + buf * 4096 + (((w << 2) + (j << 1)) << 7));
        }
      };

      float2 acc0 = {0.f, 0.f}, acc1 = {0.f, 0.f}, acc2 = {0.f, 0.f}, acc3 = {0.f, 0.f};
      STAGE(0, 0);
      asm volatile("s_waitcnt vmcnt(0)" ::: "memory");
      __syncthreads();
      for (int c = 0; c < nch; ++c) {
        const int cur = c & 1;
        if (c + 1 < nch) STAGE(c + 1, cur ^ 1);
        const float* Abuf = smem + cur * 1024 + (w << 7);   // this wave's 4 m-rows
        const float* Bbuf = smem + 2048 + cur * 4096;
        #pragma unroll
        for (int kq = 0; kq < 8; ++kq) {
          const float4 a0 = *(const float4*)(Abuf + 0 * 32 + (kq << 2));
          const float4 a1 = *(const float4*)(Abuf + 1 * 32 + (kq << 2));
          const float4 a2 = *(const float4*)(Abuf + 2 * 32 + (kq << 2));
          const float4 a3 = *(const float4*)(Abuf + 3 * 32 + (kq << 2));
          const float2 b0 = *(const float2*)(Bbuf + ((kq << 2) + 0) * 128 + (l << 1));
          const float2 b1 = *(const float2*)(Bbuf + ((kq << 2) + 1) * 128 + (l << 1));
          const float2 b2 = *(const float2*)(Bbuf + ((kq << 2) + 2) * 128 + (l << 1));
          const float2 b3 = *(const float2*)(Bbuf + ((kq << 2) + 3) * 128 + (l << 1));
          STEP(acc0, a0) STEP(acc1, a1) STEP(acc2, a2) STEP(acc3, a3)
        }
        asm volatile("s_waitcnt vmcnt(0)" ::: "memory");
        __syncthreads();
      }

      // bias + writeback
      const int cc = c0 + (l << 1);
      float2 bias;
      if (isproj) { bias.x = bpx[cc]; bias.y = bpx[cc + 1]; }
      else {
        bias.x = bix[cc - 1024] + bih[cc - 1024];
        bias.y = bix[cc - 1023] + bih[cc - 1023];
      }
      {
        const int nd0 = s_node[(w << 2) + 0];
        const int nd1 = s_node[(w << 2) + 1];
        const int nd2 = s_node[(w << 2) + 2];
        const int nd3 = s_node[(w << 2) + 3];
        if (nd0 >= 0) { float2 o; o.x = acc0.x + bias.x; o.y = acc0.y + bias.y; *(float2*)(g_buf + (size_t)nd0 * 6144 + cc) = o; }
        if (nd1 >= 0) { float2 o; o.x = acc1.x + bias.x; o.y = acc1.y + bias.y; *(float2*)(g_buf + (size_t)nd1 * 6144 + cc) = o; }
        if (nd2 >= 0) { float2 o; o.x = acc2.x + bias.x; o.y = acc2.y + bias.y; *(float2*)(g_buf + (size_t)nd2 * 6144 + cc) = o; }
        if (nd3 >= 0) { float2 o; o.x = acc3.x + bias.x; o.y = acc3.y + bias.y; *(float2*)(g_buf + (size_t)nd3 * 6144 + cc) = o; }
      }
    }
    gbar(&gen);

    // ---------------- Phase B ----------------
    for (int ni = (int)blockIdx.x; ni < M; ni += NBLK) {
      const int node = g_order[s0 + ni];
      const int p = parent[node];
      const float* gb = g_buf + (size_t)node * 6144;
      for (int j = tid; j < 1024; j += NTHR) {
        const float proj = gb[j];
        const float vi = gb[1024 + j];
        const float vo = gb[2048 + j];
        const float vf = gb[3072 + j];
        const float vu = gb[4096 + j];
        const float vr = gb[5120 + j];
        const float ig = 1.f / (1.f + expf(-vi));
        const float og = 1.f / (1.f + expf(-vo));
        const float fg = 1.f / (1.f + expf(-vf));
        const float rg = 1.f / (1.f + expf(-vr));
        const float ug = tanhf(vu);
        const float pc = (p >= 0) ? g_c[(size_t)p * 1024 + j] : 0.f;
        const float c = ig * ug + fg * pc;
        const float h = og * tanhf(c);
        const float hf = rg * h + (1.f - rg) * proj;
        g_c[(size_t)node * 1024 + j] = c;
        g_h[(size_t)node * 1024 + j] = hf;
        smem[j] = hf;
      }
      __syncthreads();
      {
        const int kbeg = w << 7;   // 8 waves x 128 k
        for (int cb = 0; cb < 192; cb += 64) {
          const int col = cb + l;
          if (col < 151) {
            float a0 = 0.f, a1 = 0.f, a2 = 0.f, a3 = 0.f;
            const float* wp = Wout + (size_t)kbeg * 151 + col;
            const float* hp = smem + kbeg;
            for (int kk = 0; kk < 128; kk += 4) {
              a0 += hp[kk + 0] * wp[(size_t)(kk + 0) * 151];
              a1 += hp[kk + 1] * wp[(size_t)(kk + 1) * 151];
              a2 += hp[kk + 2] * wp[(size_t)(kk + 2) * 151];
              a3 += hp[kk + 3] * wp[(size_t)(kk + 3) * 151];
            }
            smem[1024 + w * 152 + col] = (a0 + a1) + (a2 + a3);
          }
        }
      }
      __syncthreads();
      if (tid < 151) {
        float d = bout[tid];
        #pragma unroll
        for (int ww = 0; ww < 8; ++ww) d += smem[1024 + ww * 152 + tid];
        smem[2400 + tid] = d;
        if (node >= 8) out[(size_t)(node - 8) * 151 + tid] = d;
      }
      __syncthreads();
      if (tid < 64) {
        float bv = -3.4e38f; int bidx = 1;
        for (int cb = 0; cb < 192; cb += 64) {
          const int col = 1 + cb + tid;
          if (col < 151) {
            const float v = smem[2400 + col];
            if (v > bv) { bv = v; bidx = col; }
          }
        }
        for (int off = 32; off > 0; off >>= 1) {
          const float ov = __shfl_down(bv, off);
          const int oi = __shfl_down(bidx, off);
          if (ov > bv || (ov == bv && oi < bidx)) { bv = ov; bidx = oi; }
        }
        if (tid == 0) {
          g_commit[node] = bidx;
          if (node >= 8) out[OUT_COMMIT_OFF + node - 8] = (float)bidx;
        }
      }
      __syncthreads();
    }
    gbar(&gen);
  }
}

extern "C" void kernel_launch(void* const* d_in, const int* in_sizes, int n_in,
                              void* d_out, int out_size, void* d_ws, size_t ws_size,
                              hipStream_t stream) {
  const float* feat   = (const float*)d_in[0];
  const int*   parent = (const int*)d_in[1];
  // d_in[2] = batch_size (8), hardcoded
  const float* Wpx  = (const float*)d_in[3];
  const float* bpx  = (const float*)d_in[4];
  const float* Wix  = (const float*)d_in[5];
  const float* bix  = (const float*)d_in[6];
  const float* Wih  = (const float*)d_in[7];
  const float* bih  = (const float*)d_in[8];
  const float* Wout = (const float*)d_in[9];
  const float* bout = (const float*)d_in[10];
  const float* emb  = (const float*)d_in[11];
  float* out = (float*)d_out;

  hipLaunchKernelGGL(prep_kernel, dim3(1), dim3(1024), 0, stream, parent, emb, out);
  hipLaunchKernelGGL(lstm_main, dim3(NBLK), dim3(NTHR), 0, stream,
                     feat, parent, Wpx, bpx, Wix, bix, Wih, bih, Wout, bout, out);
}

// Round 5
// 1925.001 us; speedup vs baseline: 5.1004x; 1.7289x over previous
//
#include <hip/hip_runtime.h>
#include <math.h>

// DecoderTreeLSTM round 5.
// 1) Feature GEMM hoisted out of the level loop (pre_gemm: [1024x2048]@[2048x6144], once).
// 2) Embedding contribution precomputed for all 152 rows (emb_gemm -> g_embG, biases folded).
// 3) Per-level GEMM is only ph@Wih (K=1024, N=5120).
// 4) All GEMMs: depth-2 counted-vmcnt pipeline, triple-buffered LDS, uniform 3 loads/wave/chunk,
//    raw s_barrier (no vmcnt drain), sched_barrier(0) fences.

#define NBLK 512
#define NTHR 512
#define OUT_COMMIT_OFF (1016 * 151)

__device__ __align__(16) float g_h[1024 * 1024];
__device__ __align__(16) float g_c[1024 * 1024];
__device__ __align__(16) float g_pre[1024 * 6144];   // feat @ [Wpx|Wix] (rows 0..2047), no bias
__device__ __align__(16) float g_gate[1024 * 5120];  // final gate pre-activations
__device__ __align__(16) float g_embG[152 * 6144];   // emb @ W[2048:2248] + biases
__device__ __align__(16) float g_embpad[160 * 224];
__device__ __align__(16) float g_zero[128];
__device__ int   g_commit[1024];
__device__ int   g_lvl_start[1025];
__device__ int   g_order[1024];
__device__ int   g_numlvl;
__device__ unsigned int g_barcnt;

__device__ __forceinline__ void gload_lds16(const float* g, float* s) {
  __builtin_amdgcn_global_load_lds(
      (const __attribute__((address_space(1))) void*)g,
      (__attribute__((address_space(3))) void*)s, 16, 0, 0);
}

__device__ __forceinline__ void gbar(unsigned int* gen) {
  __syncthreads();
  if (threadIdx.x == 0) {
    ++(*gen);
    __hip_atomic_fetch_add(&g_barcnt, 1u, __ATOMIC_RELEASE, __HIP_MEMORY_SCOPE_AGENT);
    const unsigned int target = (unsigned int)NBLK * (*gen);
    while (__hip_atomic_load(&g_barcnt, __ATOMIC_RELAXED, __HIP_MEMORY_SCOPE_AGENT) < target) {
      __builtin_amdgcn_s_sleep(8);
    }
    __builtin_amdgcn_fence(__ATOMIC_ACQUIRE, "agent");
  }
  __syncthreads();
}

#define STEP(ACC, AV)                                  \
  ACC.x += AV.x * b0.x; ACC.y += AV.x * b0.y;          \
  ACC.x += AV.y * b1.x; ACC.y += AV.y * b1.y;          \
  ACC.x += AV.z * b2.x; ACC.y += AV.z * b2.y;          \
  ACC.x += AV.w * b3.x; ACC.y += AV.w * b3.y;

__device__ __forceinline__ void tile_fma(const float* __restrict__ Ab,
                                         const float* __restrict__ Bb,
                                         int l, float2* acc) {
  #pragma unroll
  for (int kq = 0; kq < 8; ++kq) {
    const float4 a0 = *(const float4*)(Ab + 0 * 32 + (kq << 2));
    const float4 a1 = *(const float4*)(Ab + 1 * 32 + (kq << 2));
    const float4 a2 = *(const float4*)(Ab + 2 * 32 + (kq << 2));
    const float4 a3 = *(const float4*)(Ab + 3 * 32 + (kq << 2));
    const float2 b0 = *(const float2*)(Bb + ((kq << 2) + 0) * 128 + (l << 1));
    const float2 b1 = *(const float2*)(Bb + ((kq << 2) + 1) * 128 + (l << 1));
    const float2 b2 = *(const float2*)(Bb + ((kq << 2) + 2) * 128 + (l << 1));
    const float2 b3 = *(const float2*)(Bb + ((kq << 2) + 3) * 128 + (l << 1));
    STEP(acc[0], a0) STEP(acc[1], a1) STEP(acc[2], a2) STEP(acc[3], a3)
  }
}

// Pipeline step waits: chunk c landed (3/wave for c+1 may remain in flight)
#define PIPE_WAIT(c, nch)                                                       \
  __builtin_amdgcn_sched_barrier(0);                                            \
  if ((c) + 1 < (nch)) { asm volatile("s_waitcnt vmcnt(3) lgkmcnt(0)" ::: "memory"); } \
  else                 { asm volatile("s_waitcnt vmcnt(0) lgkmcnt(0)" ::: "memory"); } \
  __builtin_amdgcn_s_barrier();                                                 \
  __builtin_amdgcn_sched_barrier(0);

#define TILE_DRAIN()                                                            \
  asm volatile("s_waitcnt vmcnt(0) lgkmcnt(0)" ::: "memory");                   \
  __builtin_amdgcn_s_barrier();

// ---------------------------------------------------------------------------
__global__ void prep_kernel(const int* __restrict__ parent,
                            const float* __restrict__ emb,
                            float* __restrict__ out) {
  __shared__ int lvl[1024];
  __shared__ int cnt[1024];
  __shared__ int changed;
  const int i = threadIdx.x;
  const int p = parent[i];
  lvl[i] = (p < 0) ? 0 : -1;
  for (;;) {
    if (i == 0) changed = 0;
    __syncthreads();
    if (lvl[i] < 0 && lvl[p] >= 0) { lvl[i] = lvl[p] + 1; changed = 1; }
    __syncthreads();
    const int ch = changed;
    __syncthreads();
    if (ch == 0) break;
  }
  cnt[i] = 0;
  __syncthreads();
  atomicAdd(&cnt[lvl[i]], 1);
  __syncthreads();
  if (i == 0) {
    int acc = 0, nl = 0;
    for (int l = 0; l < 1024; ++l) {
      g_lvl_start[l] = acc;
      if (cnt[l] > 0) nl = l + 1;
      acc += cnt[l];
    }
    g_lvl_start[1024] = acc;
    g_numlvl = nl;
    g_barcnt = 0u;
  }
  __syncthreads();
  cnt[i] = 0;
  __syncthreads();
  const int pos = g_lvl_start[lvl[i]] + atomicAdd(&cnt[lvl[i]], 1);
  g_order[pos] = i;
  for (int j = i; j < 160 * 224; j += 1024) {
    const int r = j / 224, cc = j - r * 224;
    g_embpad[j] = (r < 152 && cc < 200) ? emb[r * 200 + cc] : 0.0f;
  }
  if (i < 128) g_zero[i] = 0.0f;
  if (i < 8) out[OUT_COMMIT_OFF + 1016 + i] = 0.0f;
}

// ---------------------------------------------------------------------------
// embG[r][c] = sum_k embpad[r][k] * W*[2048+k][c]  + bias(c),  r<152, c<6144
// 240 tiles of 32x128, K=224 (7 chunks).
// ---------------------------------------------------------------------------
__global__ __launch_bounds__(NTHR, 4) void emb_gemm(
    const float* __restrict__ Wpx, const float* __restrict__ Wix,
    const float* __restrict__ bpx, const float* __restrict__ bix,
    const float* __restrict__ bih) {
  __shared__ __align__(16) float smem[15360];
  const int tid = threadIdx.x, w = tid >> 6, l = tid & 63;
  const int t = blockIdx.x;
  const int mt = t / 48, ct = t - (t / 48) * 48;
  const int c0 = ct << 7;
  const bool isproj = ct < 8;
  const float* W1 = isproj ? Wpx : Wix;
  const size_t N1 = isproj ? 1024 : 5120;
  const int c0x = isproj ? c0 : c0 - 1024;
  const int arow = (mt << 5) + (w << 2) + ((l & 31) >> 3);
  const int koff = (l & 7) << 2;
  const int brow0 = (w << 2) + (l >> 5);
  const int bcol = (l & 31) << 2;

  auto STAGE = [&](int c, int buf) {
    float* base = smem + buf * 5120;
    const int kb = c << 5;
    const float* srcA = g_embpad + arow * 224 + kb + koff;
    if (l < 32) gload_lds16(srcA, base + (w << 7));
    #pragma unroll
    for (int j = 0; j < 2; ++j) {
      const int k = kb + brow0 + (j << 1);
      const float* srcB = (k < 200) ? (W1 + (size_t)(2048 + k) * N1 + c0x + bcol) : g_zero;
      gload_lds16(srcB, base + 1024 + (((w << 2) + (j << 1)) << 7));
    }
  };

  float2 acc[4] = {{0.f,0.f},{0.f,0.f},{0.f,0.f},{0.f,0.f}};
  const int nch = 7;
  TILE_DRAIN();
  STAGE(0, 0); STAGE(1, 1);
  for (int c = 0; c < nch; ++c) {
    PIPE_WAIT(c, nch);
    if (c + 2 < nch) STAGE(c + 2, (c + 2) % 3);
    const int bb = c % 3;
    tile_fma(smem + bb * 5120 + (w << 7), smem + bb * 5120 + 1024, l, acc);
  }
  const int cc = c0 + (l << 1);
  float2 bias;
  if (isproj) { bias.x = bpx[cc]; bias.y = bpx[cc + 1]; }
  else { bias.x = bix[cc - 1024] + bih[cc - 1024]; bias.y = bix[cc - 1023] + bih[cc - 1023]; }
  #pragma unroll
  for (int i = 0; i < 4; ++i) {
    const int r = (mt << 5) + (w << 2) + i;
    if (r < 152) {
      float2 o = { acc[i].x + bias.x, acc[i].y + bias.y };
      *(float2*)(g_embG + (size_t)r * 6144 + cc) = o;
    }
  }
}

// ---------------------------------------------------------------------------
// g_pre[m][c] = sum_{k<2048} feat[m][k] * W*[k][c]   (no bias)
// 1536 tiles (32 mt x 48 ct), XCD-pinned: ct%8 == blockIdx%8, 3 passes.
// ---------------------------------------------------------------------------
__global__ __launch_bounds__(NTHR, 4) void pre_gemm(
    const float* __restrict__ feat,
    const float* __restrict__ Wpx, const float* __restrict__ Wix) {
  __shared__ __align__(16) float smem[15360];
  const int tid = threadIdx.x, w = tid >> 6, l = tid & 63;
  const int b = blockIdx.x;
  const int xcd = b & 7, q = b >> 3;
  const int koff = (l & 7) << 2;
  const int brow0 = (w << 2) + (l >> 5);
  const int bcol = (l & 31) << 2;

  for (int p = 0; p < 3; ++p) {
    const int idx = q + (p << 6);            // 0..191
    const int ct = ((idx >> 5) << 3) | xcd;  // 6 column tiles per xcd
    const int mt = idx & 31;
    const int c0 = ct << 7;
    const bool isproj = ct < 8;
    const float* W1 = isproj ? Wpx : Wix;
    const size_t N1 = isproj ? 1024 : 5120;
    const int c0x = isproj ? c0 : c0 - 1024;
    const int arow = (mt << 5) + (w << 2) + ((l & 31) >> 3);
    const float* asrc = feat + (size_t)arow * 2048 + koff;

    auto STAGE = [&](int c, int buf) {
      float* base = smem + buf * 5120;
      const int kb = c << 5;
      if (l < 32) gload_lds16(asrc + kb, base + (w << 7));
      #pragma unroll
      for (int j = 0; j < 2; ++j) {
        const int k = kb + brow0 + (j << 1);
        gload_lds16(W1 + (size_t)k * N1 + c0x + bcol,
                    base + 1024 + (((w << 2) + (j << 1)) << 7));
      }
    };

    float2 acc[4] = {{0.f,0.f},{0.f,0.f},{0.f,0.f},{0.f,0.f}};
    const int nch = 64;
    TILE_DRAIN();
    STAGE(0, 0); STAGE(1, 1);
    for (int c = 0; c < nch; ++c) {
      PIPE_WAIT(c, nch);
      if (c + 2 < nch) STAGE(c + 2, (c + 2) % 3);
      const int bb = c % 3;
      tile_fma(smem + bb * 5120 + (w << 7), smem + bb * 5120 + 1024, l, acc);
    }
    const int cc = c0 + (l << 1);
    #pragma unroll
    for (int i = 0; i < 4; ++i) {
      const int r = (mt << 5) + (w << 2) + i;
      *(float2*)(g_pre + (size_t)r * 6144 + cc) = acc[i];
    }
  }
}

// ---------------------------------------------------------------------------
// Main persistent kernel: per level, h-GEMM (K=1024, N=5120) + phase B.
// ---------------------------------------------------------------------------
__global__ __launch_bounds__(NTHR, 4) void lstm_main(
    const int* __restrict__ parent,
    const float* __restrict__ Wih,
    const float* __restrict__ Wout, const float* __restrict__ bout,
    float* __restrict__ out) {
  __shared__ __align__(16) float smem[15360];
  __shared__ int s_node[32], s_erow[32], s_ppar[32];
  unsigned int gen = 0;
  const int tid = threadIdx.x;
  const int w = tid >> 6, l = tid & 63;
  const int nl = g_numlvl;
  const int koff = (l & 7) << 2;
  const int brow0 = (w << 2) + (l >> 5);
  const int bcol = (l & 31) << 2;

  for (int L = 0; L < nl; ++L) {
    const int s0 = g_lvl_start[L];
    const int M  = g_lvl_start[L + 1] - s0;
    const int nmt = (M + 31) >> 5;
    const int ntile = nmt * 40;

    // ---------------- Phase A: g_gate = ph @ Wih + g_pre[,1024:] + embG[er,1024:]
    for (int t = (int)blockIdx.x; t < ntile; t += NBLK) {
      const int mt = t / 40, ct = t - (t / 40) * 40;
      const int c0 = ct << 7;

      TILE_DRAIN();
      if (tid < 32) {
        const int m = (mt << 5) + tid;
        int nd = -1, er = 0, pp = -1;
        if (m < M) { nd = g_order[s0 + m]; pp = parent[nd]; er = (pp < 0) ? 0 : g_commit[pp]; }
        s_node[tid] = nd; s_erow[tid] = er; s_ppar[tid] = pp;
      }
      __syncthreads();
      const int rsel = (w << 2) + ((l & 31) >> 3);
      const int mypp = s_ppar[rsel];
      const float* asrc = (mypp >= 0) ? (g_h + ((size_t)mypp << 10) + koff) : g_zero;
      const bool rootA = (mypp < 0);

      auto STAGE = [&](int c, int buf) {
        float* base = smem + buf * 5120;
        const int kb = c << 5;
        const float* srcA = rootA ? g_zero : (asrc + kb);
        if (l < 32) gload_lds16(srcA, base + (w << 7));
        #pragma unroll
        for (int j = 0; j < 2; ++j) {
          const int k = kb + brow0 + (j << 1);
          gload_lds16(Wih + (size_t)k * 5120 + c0 + bcol,
                      base + 1024 + (((w << 2) + (j << 1)) << 7));
        }
      };

      float2 acc[4] = {{0.f,0.f},{0.f,0.f},{0.f,0.f},{0.f,0.f}};
      const int nch = 32;
      STAGE(0, 0); STAGE(1, 1);
      for (int c = 0; c < nch; ++c) {
        PIPE_WAIT(c, nch);
        if (c + 2 < nch) STAGE(c + 2, (c + 2) % 3);
        const int bb = c % 3;
        tile_fma(smem + bb * 5120 + (w << 7), smem + bb * 5120 + 1024, l, acc);
      }
      const int cc = c0 + (l << 1);
      #pragma unroll
      for (int i = 0; i < 4; ++i) {
        const int nd = s_node[(w << 2) + i];
        if (nd >= 0) {
          const int er = s_erow[(w << 2) + i];
          const float2 pv = *(const float2*)(g_pre + (size_t)nd * 6144 + 1024 + cc);
          const float2 ev = *(const float2*)(g_embG + (size_t)er * 6144 + 1024 + cc);
          float2 o = { acc[i].x + pv.x + ev.x, acc[i].y + pv.y + ev.y };
          *(float2*)(g_gate + (size_t)nd * 5120 + cc) = o;
        }
      }
    }
    gbar(&gen);

    // ---------------- Phase B ----------------
    for (int ni = (int)blockIdx.x; ni < M; ni += NBLK) {
      const int node = g_order[s0 + ni];
      const int p = parent[node];
      const int er = (p < 0) ? 0 : g_commit[p];
      const float* pre = g_pre + (size_t)node * 6144;
      const float* eg  = g_embG + (size_t)er * 6144;
      const float* gt  = g_gate + (size_t)node * 5120;
      for (int j = tid; j < 1024; j += NTHR) {
        const float proj = pre[j] + eg[j];
        const float vi = gt[j];
        const float vo = gt[1024 + j];
        const float vf = gt[2048 + j];
        const float vu = gt[3072 + j];
        const float vr = gt[4096 + j];
        const float ig = 1.f / (1.f + expf(-vi));
        const float og = 1.f / (1.f + expf(-vo));
        const float fg = 1.f / (1.f + expf(-vf));
        const float rg = 1.f / (1.f + expf(-vr));
        const float ug = tanhf(vu);
        const float pc = (p >= 0) ? g_c[(size_t)p * 1024 + j] : 0.f;
        const float c = ig * ug + fg * pc;
        const float h = og * tanhf(c);
        const float hf = rg * h + (1.f - rg) * proj;
        g_c[(size_t)node * 1024 + j] = c;
        g_h[(size_t)node * 1024 + j] = hf;
        smem[j] = hf;
      }
      __syncthreads();
      {
        const int kbeg = w << 7;
        for (int cb = 0; cb < 192; cb += 64) {
          const int col = cb + l;
          if (col < 151) {
            float a0 = 0.f, a1 = 0.f, a2 = 0.f, a3 = 0.f;
            const float* wp = Wout + (size_t)kbeg * 151 + col;
            const float* hp = smem + kbeg;
            for (int kk = 0; kk < 128; kk += 4) {
              a0 += hp[kk + 0] * wp[(size_t)(kk + 0) * 151];
              a1 += hp[kk + 1] * wp[(size_t)(kk + 1) * 151];
              a2 += hp[kk + 2] * wp[(size_t)(kk + 2) * 151];
              a3 += hp[kk + 3] * wp[(size_t)(kk + 3) * 151];
            }
            smem[1024 + w * 152 + col] = (a0 + a1) + (a2 + a3);
          }
        }
      }
      __syncthreads();
      if (tid < 151) {
        float d = bout[tid];
        #pragma unroll
        for (int ww = 0; ww < 8; ++ww) d += smem[1024 + ww * 152 + tid];
        smem[2400 + tid] = d;
        if (node >= 8) out[(size_t)(node - 8) * 151 + tid] = d;
      }
      __syncthreads();
      if (tid < 64) {
        float bv = -3.4e38f; int bidx = 1;
        for (int cb = 0; cb < 192; cb += 64) {
          const int col = 1 + cb + tid;
          if (col < 151) {
            const float v = smem[2400 + col];
            if (v > bv) { bv = v; bidx = col; }
          }
        }
        for (int off = 32; off > 0; off >>= 1) {
          const float ov = __shfl_down(bv, off);
          const int oi = __shfl_down(bidx, off);
          if (ov > bv || (ov == bv && oi < bidx)) { bv = ov; bidx = oi; }
        }
        if (tid == 0) {
          g_commit[node] = bidx;
          if (node >= 8) out[OUT_COMMIT_OFF + node - 8] = (float)bidx;
        }
      }
      __syncthreads();
    }
    gbar(&gen);
  }
}

extern "C" void kernel_launch(void* const* d_in, const int* in_sizes, int n_in,
                              void* d_out, int out_size, void* d_ws, size_t ws_size,
                              hipStream_t stream) {
  const float* feat   = (const float*)d_in[0];
  const int*   parent = (const int*)d_in[1];
  // d_in[2] = batch_size (8), hardcoded
  const float* Wpx  = (const float*)d_in[3];
  const float* bpx  = (const float*)d_in[4];
  const float* Wix  = (const float*)d_in[5];
  const float* bix  = (const float*)d_in[6];
  const float* Wih  = (const float*)d_in[7];
  const float* bih  = (const float*)d_in[8];
  const float* Wout = (const float*)d_in[9];
  const float* bout = (const float*)d_in[10];
  const float* emb  = (const float*)d_in[11];
  float* out = (float*)d_out;

  hipLaunchKernelGGL(prep_kernel, dim3(1), dim3(1024), 0, stream, parent, emb, out);
  hipLaunchKernelGGL(emb_gemm, dim3(240), dim3(NTHR), 0, stream, Wpx, Wix, bpx, bix, bih);
  hipLaunchKernelGGL(pre_gemm, dim3(NBLK), dim3(NTHR), 0, stream, feat, Wpx, Wix);
  hipLaunchKernelGGL(lstm_main, dim3(NBLK), dim3(NTHR), 0, stream,
                     parent, Wih, Wout, bout, out);
}

// Round 6
// 1679.193 us; speedup vs baseline: 5.8470x; 1.1464x over previous
//
#include <hip/hip_runtime.h>
#include <math.h>

// DecoderTreeLSTM round 6.
// - All GEMMs: K=64 chunks, double-buffered LDS (80KB, 2 blk/CU), minimal 2-phase
//   pipeline: STAGE(next) -> compute(cur) -> vmcnt(0)+s_barrier (1 barrier/chunk).
// - gbar: 16 split counters on separate cachelines (kills same-address RMW serialization).
// - XCD-pinned column tiles (ct % 8 == blockIdx % 8) -> per-XCD Wih slice L2-resident.
// - pre_gemm: 1536 blocks, one tile each. Phase-B matvec unrolled x8.

#define NBLK 512
#define NTHR 512
#define OUT_COMMIT_OFF (1016 * 151)

__device__ __align__(16) float g_h[1024 * 1024];
__device__ __align__(16) float g_c[1024 * 1024];
__device__ __align__(16) float g_pre[1024 * 6144];   // feat @ [Wpx|Wix], no bias
__device__ __align__(16) float g_gate[1024 * 5120];  // gate pre-activations
__device__ __align__(16) float g_embG[152 * 6144];   // embpad @ W[2048:2248] + biases
__device__ __align__(16) float g_embpad[162 * 224];
__device__ __align__(16) float g_zero[128];
__device__ int   g_commit[1024];
__device__ int   g_lvl_start[1025];
__device__ int   g_order[1024];
__device__ int   g_numlvl;
__device__ unsigned int g_barcnt[512];   // 16 counters at stride 32 (128 B apart)

__device__ __forceinline__ void gload_lds16(const float* g, float* s) {
  __builtin_amdgcn_global_load_lds(
      (const __attribute__((address_space(1))) void*)g,
      (__attribute__((address_space(3))) void*)s, 16, 0, 0);
}

__device__ __forceinline__ void gbar(unsigned int* gen) {
  __syncthreads();
  if (threadIdx.x == 0) {
    ++(*gen);
    __hip_atomic_fetch_add(&g_barcnt[((unsigned)blockIdx.x & 15) << 5], 1u,
                           __ATOMIC_RELEASE, __HIP_MEMORY_SCOPE_AGENT);
    const unsigned int target = (unsigned int)NBLK * (*gen);
    for (;;) {
      unsigned int s = 0;
      #pragma unroll
      for (int i = 0; i < 16; ++i)
        s += __hip_atomic_load(&g_barcnt[i << 5], __ATOMIC_RELAXED, __HIP_MEMORY_SCOPE_AGENT);
      if (s >= target) break;
      __builtin_amdgcn_s_sleep(8);
    }
    __builtin_amdgcn_fence(__ATOMIC_ACQUIRE, "agent");
  }
  __syncthreads();
}

#define STEP(ACC, AV)                                  \
  ACC.x += AV.x * b0.x; ACC.y += AV.x * b0.y;          \
  ACC.x += AV.y * b1.x; ACC.y += AV.y * b1.y;          \
  ACC.x += AV.z * b2.x; ACC.y += AV.z * b2.y;          \
  ACC.x += AV.w * b3.x; ACC.y += AV.w * b3.y;

// One K=64 chunk: A rows (4, stride 64) broadcast, B rows [64][128], 4m x 2n per thread.
__device__ __forceinline__ void chunk_fma64(const float* __restrict__ Ab,
                                            const float* __restrict__ Bb,
                                            int l, float2* acc) {
  #pragma unroll
  for (int kq = 0; kq < 16; ++kq) {
    const float4 a0 = *(const float4*)(Ab + 0 * 64 + (kq << 2));
    const float4 a1 = *(const float4*)(Ab + 1 * 64 + (kq << 2));
    const float4 a2 = *(const float4*)(Ab + 2 * 64 + (kq << 2));
    const float4 a3 = *(const float4*)(Ab + 3 * 64 + (kq << 2));
    const float2 b0 = *(const float2*)(Bb + ((kq << 2) + 0) * 128 + (l << 1));
    const float2 b1 = *(const float2*)(Bb + ((kq << 2) + 1) * 128 + (l << 1));
    const float2 b2 = *(const float2*)(Bb + ((kq << 2) + 2) * 128 + (l << 1));
    const float2 b3 = *(const float2*)(Bb + ((kq << 2) + 3) * 128 + (l << 1));
    STEP(acc[0], a0) STEP(acc[1], a1) STEP(acc[2], a2) STEP(acc[3], a3)
  }
}

#define CHUNK_END()                                                     \
  asm volatile("s_waitcnt vmcnt(0) lgkmcnt(0)" ::: "memory");           \
  __builtin_amdgcn_s_barrier();

// ---------------------------------------------------------------------------
__global__ void prep_kernel(const int* __restrict__ parent,
                            const float* __restrict__ emb,
                            float* __restrict__ out) {
  __shared__ int lvl[1024];
  __shared__ int cnt[1024];
  __shared__ int changed;
  const int i = threadIdx.x;
  const int p = parent[i];
  lvl[i] = (p < 0) ? 0 : -1;
  for (;;) {
    if (i == 0) changed = 0;
    __syncthreads();
    if (lvl[i] < 0 && lvl[p] >= 0) { lvl[i] = lvl[p] + 1; changed = 1; }
    __syncthreads();
    const int ch = changed;
    __syncthreads();
    if (ch == 0) break;
  }
  cnt[i] = 0;
  __syncthreads();
  atomicAdd(&cnt[lvl[i]], 1);
  __syncthreads();
  if (i == 0) {
    int acc = 0, nl = 0;
    for (int l = 0; l < 1024; ++l) {
      g_lvl_start[l] = acc;
      if (cnt[l] > 0) nl = l + 1;
      acc += cnt[l];
    }
    g_lvl_start[1024] = acc;
    g_numlvl = nl;
  }
  __syncthreads();
  cnt[i] = 0;
  __syncthreads();
  const int pos = g_lvl_start[lvl[i]] + atomicAdd(&cnt[lvl[i]], 1);
  g_order[pos] = i;
  for (int j = i; j < 162 * 224; j += 1024) {
    const int r = j / 224, cc = j - r * 224;
    g_embpad[j] = (r < 152 && cc < 200) ? emb[r * 200 + cc] : 0.0f;
  }
  if (i < 512) g_barcnt[i] = 0u;
  if (i < 128) g_zero[i] = 0.0f;
  if (i < 8) out[OUT_COMMIT_OFF + 1016 + i] = 0.0f;
}

// ---------------------------------------------------------------------------
// emb_gemm: 240 blocks (5 mt x 48 ct). K=224 padded to 256 (4 chunks of 64).
// ---------------------------------------------------------------------------
__global__ __launch_bounds__(NTHR, 4) void emb_gemm(
    const float* __restrict__ Wpx, const float* __restrict__ Wix,
    const float* __restrict__ bpx, const float* __restrict__ bix,
    const float* __restrict__ bih) {
  __shared__ __align__(16) float smem[20480];
  const int tid = threadIdx.x, w = tid >> 6, l = tid & 63;
  const int mt = blockIdx.x / 48, ct = blockIdx.x % 48;
  const int c0 = ct << 7;
  const bool isproj = ct < 8;
  const float* W1 = isproj ? Wpx : Wix;
  const size_t N1 = isproj ? 1024 : 5120;
  const int c0x = isproj ? c0 : c0 - 1024;
  const int arow = (mt << 5) + (w << 2) + (l >> 4);
  const float* asrc = g_embpad + arow * 224 + ((l & 15) << 2);
  const int brow = (w << 3) + (l >> 5);
  const int bcol = (l & 31) << 2;

  auto STAGE = [&](int c, int buf) {
    float* base = smem + buf * 10240;
    const int kb = c << 6;
    gload_lds16(asrc + kb, base + (w << 8));
    #pragma unroll
    for (int j = 0; j < 4; ++j) {
      const int k = kb + brow + (j << 1);
      const float* srcB = (k < 200) ? (W1 + (size_t)(2048 + k) * N1 + c0x + bcol)
                                    : (g_zero + bcol);
      gload_lds16(srcB, base + 2048 + (((w << 3) + (j << 1)) << 7));
    }
  };

  float2 acc[4] = {{0.f,0.f},{0.f,0.f},{0.f,0.f},{0.f,0.f}};
  STAGE(0, 0);
  asm volatile("s_waitcnt vmcnt(0)" ::: "memory");
  __builtin_amdgcn_s_barrier();
  const int nch = 4;
  for (int c = 0; c < nch; ++c) {
    if (c + 1 < nch) STAGE(c + 1, (c + 1) & 1);
    const int cur = c & 1;
    chunk_fma64(smem + cur * 10240 + (w << 8), smem + cur * 10240 + 2048, l, acc);
    CHUNK_END();
  }
  const int cc = c0 + (l << 1);
  float2 bias;
  if (isproj) { bias.x = bpx[cc]; bias.y = bpx[cc + 1]; }
  else { bias.x = bix[cc - 1024] + bih[cc - 1024]; bias.y = bix[cc - 1023] + bih[cc - 1023]; }
  #pragma unroll
  for (int i = 0; i < 4; ++i) {
    const int r = (mt << 5) + (w << 2) + i;
    if (r < 152) {
      float2 o = { acc[i].x + bias.x, acc[i].y + bias.y };
      *(float2*)(g_embG + (size_t)r * 6144 + cc) = o;
    }
  }
}

// ---------------------------------------------------------------------------
// pre_gemm: 1536 blocks, one 32x128 tile each, K=2048 (32 chunks), XCD-pinned ct.
// ---------------------------------------------------------------------------
__global__ __launch_bounds__(NTHR, 4) void pre_gemm(
    const float* __restrict__ feat,
    const float* __restrict__ Wpx, const float* __restrict__ Wix) {
  __shared__ __align__(16) float smem[20480];
  const int tid = threadIdx.x, w = tid >> 6, l = tid & 63;
  const int b = blockIdx.x;
  const int x = b & 7, u = b >> 3;            // u in [0,192)
  const int ct = x + ((u % 6) << 3);          // 48 col tiles, pinned to xcd
  const int mt = u / 6;                       // 32 row tiles
  const int c0 = ct << 7;
  const bool isproj = ct < 8;
  const float* W1 = isproj ? Wpx : Wix;
  const size_t N1 = isproj ? 1024 : 5120;
  const int c0x = isproj ? c0 : c0 - 1024;
  const int arow = (mt << 5) + (w << 2) + (l >> 4);
  const float* asrc = feat + (size_t)arow * 2048 + ((l & 15) << 2);
  const int brow = (w << 3) + (l >> 5);
  const int bcol = (l & 31) << 2;

  auto STAGE = [&](int c, int buf) {
    float* base = smem + buf * 10240;
    const int kb = c << 6;
    gload_lds16(asrc + kb, base + (w << 8));
    #pragma unroll
    for (int j = 0; j < 4; ++j) {
      gload_lds16(W1 + (size_t)(kb + brow + (j << 1)) * N1 + c0x + bcol,
                  base + 2048 + (((w << 3) + (j << 1)) << 7));
    }
  };

  float2 acc[4] = {{0.f,0.f},{0.f,0.f},{0.f,0.f},{0.f,0.f}};
  STAGE(0, 0);
  asm volatile("s_waitcnt vmcnt(0)" ::: "memory");
  __builtin_amdgcn_s_barrier();
  const int nch = 32;
  for (int c = 0; c < nch; ++c) {
    if (c + 1 < nch) STAGE(c + 1, (c + 1) & 1);
    const int cur = c & 1;
    chunk_fma64(smem + cur * 10240 + (w << 8), smem + cur * 10240 + 2048, l, acc);
    CHUNK_END();
  }
  const int cc = c0 + (l << 1);
  #pragma unroll
  for (int i = 0; i < 4; ++i) {
    const int r = (mt << 5) + (w << 2) + i;
    *(float2*)(g_pre + (size_t)r * 6144 + cc) = acc[i];
  }
}

// ---------------------------------------------------------------------------
// Main persistent kernel: per level, h-GEMM (K=1024, N=5120, 16 chunks) + phase B.
// ---------------------------------------------------------------------------
__global__ __launch_bounds__(NTHR, 4) void lstm_main(
    const int* __restrict__ parent,
    const float* __restrict__ Wih,
    const float* __restrict__ Wout, const float* __restrict__ bout,
    float* __restrict__ out) {
  __shared__ __align__(16) float smem[20480];
  unsigned int gen = 0;
  const int tid = threadIdx.x;
  const int w = tid >> 6, l = tid & 63;
  const int nl = g_numlvl;
  const int x = (int)blockIdx.x & 7, u = (int)blockIdx.x >> 3;   // u in [0,64)
  const int brow = (w << 3) + (l >> 5);
  const int bcol = (l & 31) << 2;
  const int aoff = (l & 15) << 2;

  for (int L = 0; L < nl; ++L) {
    const int s0 = g_lvl_start[L];
    const int M  = g_lvl_start[L + 1] - s0;
    const int nmt = (M + 31) >> 5;

    // ---------------- Phase A: g_gate = ph @ Wih + g_pre[:,1024:] + embG[er,1024:]
    const int tpx = nmt * 5;   // tiles per xcd (5 col tiles of 128 over 5120)
    for (int t = u; t < tpx; t += 64) {
      const int mt = t / 5;
      const int ct = x + ((t % 5) << 3);
      const int c0 = ct << 7;

      // A-staging meta (this thread stages row mA of the tile)
      const int mA = (mt << 5) + (w << 2) + (l >> 4);
      const int ndA = (mA < M) ? g_order[s0 + mA] : -1;
      const int ppA = (ndA >= 0) ? parent[ndA] : -1;
      const float* asrc = (ppA >= 0) ? (g_h + ((size_t)ppA << 10) + aoff)
                                     : (g_zero + aoff);
      const bool rootA = (ppA < 0);

      auto STAGE = [&](int c, int buf) {
        float* base = smem + buf * 10240;
        const int kb = c << 6;
        gload_lds16(rootA ? asrc : (asrc + kb), base + (w << 8));
        #pragma unroll
        for (int j = 0; j < 4; ++j) {
          gload_lds16(Wih + (size_t)(kb + brow + (j << 1)) * 5120 + c0 + bcol,
                      base + 2048 + (((w << 3) + (j << 1)) << 7));
        }
      };

      float2 acc[4] = {{0.f,0.f},{0.f,0.f},{0.f,0.f},{0.f,0.f}};
      STAGE(0, 0);
      asm volatile("s_waitcnt vmcnt(0)" ::: "memory");
      __builtin_amdgcn_s_barrier();
      const int nch = 16;
      for (int c = 0; c < nch; ++c) {
        if (c + 1 < nch) STAGE(c + 1, (c + 1) & 1);
        const int cur = c & 1;
        chunk_fma64(smem + cur * 10240 + (w << 8), smem + cur * 10240 + 2048, l, acc);
        CHUNK_END();
      }

      const int cc = c0 + (l << 1);
      #pragma unroll
      for (int i = 0; i < 4; ++i) {
        const int m = (mt << 5) + (w << 2) + i;
        if (m < M) {
          const int nd = g_order[s0 + m];
          const int pp = parent[nd];
          const int er = (pp < 0) ? 0 : g_commit[pp];
          const float2 pv = *(const float2*)(g_pre + (size_t)nd * 6144 + 1024 + cc);
          const float2 ev = *(const float2*)(g_embG + (size_t)er * 6144 + 1024 + cc);
          float2 o = { acc[i].x + pv.x + ev.x, acc[i].y + pv.y + ev.y };
          *(float2*)(g_gate + (size_t)nd * 5120 + cc) = o;
        }
      }
    }
    gbar(&gen);

    // ---------------- Phase B ----------------
    for (int ni = (int)blockIdx.x; ni < M; ni += NBLK) {
      const int node = g_order[s0 + ni];
      const int p = parent[node];
      const int er = (p < 0) ? 0 : g_commit[p];
      const float* pre = g_pre + (size_t)node * 6144;
      const float* eg  = g_embG + (size_t)er * 6144;
      const float* gt  = g_gate + (size_t)node * 5120;
      for (int j = tid; j < 1024; j += NTHR) {
        const float proj = pre[j] + eg[j];
        const float vi = gt[j];
        const float vo = gt[1024 + j];
        const float vf = gt[2048 + j];
        const float vu = gt[3072 + j];
        const float vr = gt[4096 + j];
        const float ig = 1.f / (1.f + expf(-vi));
        const float og = 1.f / (1.f + expf(-vo));
        const float fg = 1.f / (1.f + expf(-vf));
        const float rg = 1.f / (1.f + expf(-vr));
        const float ug = tanhf(vu);
        const float pc = (p >= 0) ? g_c[(size_t)p * 1024 + j] : 0.f;
        const float c = ig * ug + fg * pc;
        const float h = og * tanhf(c);
        const float hf = rg * h + (1.f - rg) * proj;
        g_c[(size_t)node * 1024 + j] = c;
        g_h[(size_t)node * 1024 + j] = hf;
        smem[j] = hf;
      }
      __syncthreads();
      {
        const int kbeg = w << 7;
        for (int cb = 0; cb < 192; cb += 64) {
          const int col = cb + l;
          if (col < 151) {
            float a0 = 0.f, a1 = 0.f, a2 = 0.f, a3 = 0.f;
            float a4 = 0.f, a5 = 0.f, a6 = 0.f, a7 = 0.f;
            const float* wp = Wout + (size_t)kbeg * 151 + col;
            const float* hp = smem + kbeg;
            for (int kk = 0; kk < 128; kk += 8) {
              a0 += hp[kk + 0] * wp[(size_t)(kk + 0) * 151];
              a1 += hp[kk + 1] * wp[(size_t)(kk + 1) * 151];
              a2 += hp[kk + 2] * wp[(size_t)(kk + 2) * 151];
              a3 += hp[kk + 3] * wp[(size_t)(kk + 3) * 151];
              a4 += hp[kk + 4] * wp[(size_t)(kk + 4) * 151];
              a5 += hp[kk + 5] * wp[(size_t)(kk + 5) * 151];
              a6 += hp[kk + 6] * wp[(size_t)(kk + 6) * 151];
              a7 += hp[kk + 7] * wp[(size_t)(kk + 7) * 151];
            }
            smem[1024 + w * 152 + col] = ((a0 + a1) + (a2 + a3)) + ((a4 + a5) + (a6 + a7));
          }
        }
      }
      __syncthreads();
      if (tid < 151) {
        float d = bout[tid];
        #pragma unroll
        for (int ww = 0; ww < 8; ++ww) d += smem[1024 + ww * 152 + tid];
        smem[2400 + tid] = d;
        if (node >= 8) out[(size_t)(node - 8) * 151 + tid] = d;
      }
      __syncthreads();
      if (tid < 64) {
        float bv = -3.4e38f; int bidx = 1;
        for (int cb = 0; cb < 192; cb += 64) {
          const int col = 1 + cb + tid;
          if (col < 151) {
            const float v = smem[2400 + col];
            if (v > bv) { bv = v; bidx = col; }
          }
        }
        for (int off = 32; off > 0; off >>= 1) {
          const float ov = __shfl_down(bv, off);
          const int oi = __shfl_down(bidx, off);
          if (ov > bv || (ov == bv && oi < bidx)) { bv = ov; bidx = oi; }
        }
        if (tid == 0) {
          g_commit[node] = bidx;
          if (node >= 8) out[OUT_COMMIT_OFF + node - 8] = (float)bidx;
        }
      }
      __syncthreads();
    }
    gbar(&gen);
  }
}

extern "C" void kernel_launch(void* const* d_in, const int* in_sizes, int n_in,
                              void* d_out, int out_size, void* d_ws, size_t ws_size,
                              hipStream_t stream) {
  const float* feat   = (const float*)d_in[0];
  const int*   parent = (const int*)d_in[1];
  // d_in[2] = batch_size (8), hardcoded
  const float* Wpx  = (const float*)d_in[3];
  const float* bpx  = (const float*)d_in[4];
  const float* Wix  = (const float*)d_in[5];
  const float* bix  = (const float*)d_in[6];
  const float* Wih  = (const float*)d_in[7];
  const float* bih  = (const float*)d_in[8];
  const float* Wout = (const float*)d_in[9];
  const float* bout = (const float*)d_in[10];
  const float* emb  = (const float*)d_in[11];
  float* out = (float*)d_out;

  hipLaunchKernelGGL(prep_kernel, dim3(1), dim3(1024), 0, stream, parent, emb, out);
  hipLaunchKernelGGL(emb_gemm, dim3(240), dim3(NTHR), 0, stream, Wpx, Wix, bpx, bix, bih);
  hipLaunchKernelGGL(pre_gemm, dim3(1536), dim3(NTHR), 0, stream, feat, Wpx, Wix);
  hipLaunchKernelGGL(lstm_main, dim3(NBLK), dim3(NTHR), 0, stream,
                     parent, Wih, Wout, bout, out);
}

// Round 7
// 1005.095 us; speedup vs baseline: 9.7685x; 1.6707x over previous
//
#include <hip/hip_runtime.h>
#include <math.h>

// DecoderTreeLSTM round 7: bf16x3 split-precision MFMA GEMMs (32x32x16), fragment-packed
// operands loaded direct global->VGPR (16B/lane coalesced), no LDS in GEMMs.
// A(parent h) packed by phase-B child-writes via CSR; weights packed once in pack_all.

#define NBLK 256
#define NTHR 256
#define OUT_COMMIT_OFF (1016 * 151)

typedef short bf16x8 __attribute__((ext_vector_type(8)));
typedef float f32x16 __attribute__((ext_vector_type(16)));

// ---- packed fragment buffers: idx = ((nt*KB + kb)*32 + j)*8 + kk ----
__device__ __align__(16) short g_Wih_hi[160 * 128 * 32 * 8 + 512];  // K=1024,N=5120
__device__ __align__(16) short g_Wih_lo[160 * 128 * 32 * 8 + 512];
__device__ __align__(16) short g_Wpre_hi[192 * 256 * 32 * 8 + 512]; // K=2048,N=6144
__device__ __align__(16) short g_Wpre_lo[192 * 256 * 32 * 8 + 512];
__device__ __align__(16) short g_fpk_hi[32 * 256 * 32 * 8 + 512];   // feat 1024x2048
__device__ __align__(16) short g_fpk_lo[32 * 256 * 32 * 8 + 512];
__device__ __align__(16) short g_Apk_hi[128 * 128 * 32 * 8 + 512];  // parent-h tiles
__device__ __align__(16) short g_Apk_lo[128 * 128 * 32 * 8 + 512];

__device__ __align__(16) float g_c[1024 * 1024];
__device__ __align__(16) float g_pre[1024 * 6144];
__device__ __align__(16) float g_gate[1024 * 5120];
__device__ __align__(16) float g_embG[152 * 6144];
__device__ __align__(16) float g_embpad[162 * 224];
__device__ __align__(16) float g_zero[128];
__device__ int g_commit[1024];
__device__ int g_lvl_start[1025];
__device__ int g_tile_off[1025];
__device__ int g_order[1024];
__device__ int g_prow[1024];
__device__ int g_cstart[1025];
__device__ int g_clist[1024];
__device__ int g_numlvl;
__device__ unsigned g_barcnt[512];

// ---------------- helpers ----------------
__device__ __forceinline__ unsigned short bf16_rn(float x) {
  union { float f; unsigned u; } v; v.f = x;
  unsigned r = v.u + 0x7fffu + ((v.u >> 16) & 1u);
  return (unsigned short)(r >> 16);
}
__device__ __forceinline__ float bf16_tof(unsigned short h) {
  union { float f; unsigned u; } v; v.u = ((unsigned)h) << 16; return v.f;
}
__device__ __forceinline__ void split2(float x, unsigned short& hi, unsigned short& lo) {
  hi = bf16_rn(x);
  lo = bf16_rn(x - bf16_tof(hi));
}

__device__ __forceinline__ f32x16 mfma3(bf16x8 ah, bf16x8 al, bf16x8 bh, bf16x8 bl, f32x16 c) {
  c = __builtin_amdgcn_mfma_f32_32x32x16_bf16(ah, bh, c, 0, 0, 0);
  c = __builtin_amdgcn_mfma_f32_32x32x16_bf16(ah, bl, c, 0, 0, 0);
  c = __builtin_amdgcn_mfma_f32_32x32x16_bf16(al, bh, c, 0, 0, 0);
  return c;
}

__device__ __forceinline__ void gload_lds16(const float* g, float* s) {
  __builtin_amdgcn_global_load_lds(
      (const __attribute__((address_space(1))) void*)g,
      (__attribute__((address_space(3))) void*)s, 16, 0, 0);
}

__device__ __forceinline__ void gbar(unsigned int* gen) {
  __syncthreads();
  if (threadIdx.x == 0) {
    ++(*gen);
    __hip_atomic_fetch_add(&g_barcnt[((unsigned)blockIdx.x & 15) << 5], 1u,
                           __ATOMIC_RELEASE, __HIP_MEMORY_SCOPE_AGENT);
    const unsigned int target = (unsigned int)NBLK * (*gen);
    for (;;) {
      unsigned int s = 0;
      #pragma unroll
      for (int i = 0; i < 16; ++i)
        s += __hip_atomic_load(&g_barcnt[i << 5], __ATOMIC_RELAXED, __HIP_MEMORY_SCOPE_AGENT);
      if (s >= target) break;
      __builtin_amdgcn_s_sleep(8);
    }
    __builtin_amdgcn_fence(__ATOMIC_ACQUIRE, "agent");
  }
  __syncthreads();
}

// ---------------------------------------------------------------------------
// Prep: levels, order, tile offsets, prow, children CSR, embpad, zero lvl0 A.
// ---------------------------------------------------------------------------
__global__ void prep_kernel(const int* __restrict__ parent,
                            const float* __restrict__ emb,
                            float* __restrict__ out) {
  __shared__ int lvl[1024];
  __shared__ int cnt[1024];
  __shared__ int c2[1024];
  __shared__ int changed;
  const int i = threadIdx.x;
  const int p = parent[i];
  lvl[i] = (p < 0) ? 0 : -1;
  for (;;) {
    if (i == 0) changed = 0;
    __syncthreads();
    if (lvl[i] < 0 && lvl[p] >= 0) { lvl[i] = lvl[p] + 1; changed = 1; }
    __syncthreads();
    const int ch = changed;
    __syncthreads();
    if (ch == 0) break;
  }
  cnt[i] = 0;
  __syncthreads();
  atomicAdd(&cnt[lvl[i]], 1);
  __syncthreads();
  if (i == 0) {
    int acc = 0, nl = 0, ta = 0;
    for (int l2 = 0; l2 < 1024; ++l2) {
      g_lvl_start[l2] = acc;
      g_tile_off[l2] = ta;
      if (cnt[l2] > 0) nl = l2 + 1;
      acc += cnt[l2];
      ta += (cnt[l2] + 31) >> 5;
    }
    g_lvl_start[1024] = acc;
    g_tile_off[1024] = ta;
    g_numlvl = nl;
  }
  __syncthreads();
  // order + prow
  cnt[i] = 0;
  __syncthreads();
  {
    const int ni = atomicAdd(&cnt[lvl[i]], 1);
    g_order[g_lvl_start[lvl[i]] + ni] = i;
    g_prow[i] = ((g_tile_off[lvl[i]] + (ni >> 5)) << 5) | (ni & 31);
  }
  __syncthreads();
  // children CSR
  cnt[i] = 0;
  __syncthreads();
  if (p >= 0) atomicAdd(&cnt[p], 1);
  __syncthreads();
  if (i == 0) {
    int a2 = 0;
    for (int n2 = 0; n2 < 1024; ++n2) { g_cstart[n2] = a2; a2 += cnt[n2]; }
    g_cstart[1024] = a2;
  }
  __syncthreads();
  c2[i] = 0;
  __syncthreads();
  if (p >= 0) {
    const int q = g_cstart[p] + atomicAdd(&c2[p], 1);
    g_clist[q] = i;
  }
  // embpad [162][224]
  for (int j = i; j < 162 * 224; j += 1024) {
    const int r = j / 224, cc = j - r * 224;
    g_embpad[j] = (r < 152 && cc < 200) ? emb[r * 200 + cc] : 0.0f;
  }
  __syncthreads();
  // zero level-0 A tiles (roots: ph = 0)
  {
    const int n0 = g_tile_off[1] * 32768;
    for (int e = i; e < n0; e += 1024) { g_Apk_hi[e] = 0; g_Apk_lo[e] = 0; }
  }
  if (i < 512) g_barcnt[i] = 0u;
  if (i < 128) g_zero[i] = 0.0f;
  if (i < 8) out[OUT_COMMIT_OFF + 1016 + i] = 0.0f;
}

// ---------------------------------------------------------------------------
// pack_all: hi/lo bf16 fragment packing of Wih, [Wpx|Wix] rows 0..2047, feat.
// ---------------------------------------------------------------------------
#define U_WIH  (160 * 128 * 32)
#define U_WPRE (192 * 256 * 32)
#define U_FEAT (32 * 256 * 32)
__global__ void pack_all(const float* __restrict__ Wpx, const float* __restrict__ Wix,
                         const float* __restrict__ Wih, const float* __restrict__ feat) {
  const int tot = U_WIH + U_WPRE + U_FEAT;
  for (int u = blockIdx.x * blockDim.x + threadIdx.x; u < tot; u += gridDim.x * blockDim.x) {
    if (u < U_WIH) {
      const int j = u & 31, kb = (u >> 5) & 127, nt = u >> 12;
      const int n = nt * 32 + j;
      #pragma unroll
      for (int kk = 0; kk < 8; ++kk) {
        unsigned short h, l;
        split2(Wih[(size_t)(kb * 8 + kk) * 5120 + n], h, l);
        g_Wih_hi[(size_t)u * 8 + kk] = (short)h;
        g_Wih_lo[(size_t)u * 8 + kk] = (short)l;
      }
    } else if (u < U_WIH + U_WPRE) {
      const int u2 = u - U_WIH;
      const int j = u2 & 31, kb = (u2 >> 5) & 255, nt = u2 >> 13;
      const int n = nt * 32 + j;
      #pragma unroll
      for (int kk = 0; kk < 8; ++kk) {
        const int k = kb * 8 + kk;
        const float v = (n < 1024) ? Wpx[(size_t)k * 1024 + n]
                                   : Wix[(size_t)k * 5120 + (n - 1024)];
        unsigned short h, l; split2(v, h, l);
        g_Wpre_hi[(size_t)u2 * 8 + kk] = (short)h;
        g_Wpre_lo[(size_t)u2 * 8 + kk] = (short)l;
      }
    } else {
      const int u3 = u - U_WIH - U_WPRE;
      const int j = u3 & 31, kb = (u3 >> 5) & 255, mt = u3 >> 13;
      const int m = mt * 32 + j;
      #pragma unroll
      for (int kk = 0; kk < 8; ++kk) {
        unsigned short h, l;
        split2(feat[(size_t)m * 2048 + kb * 8 + kk], h, l);
        g_fpk_hi[(size_t)u3 * 8 + kk] = (short)h;
        g_fpk_lo[(size_t)u3 * 8 + kk] = (short)l;
      }
    }
  }
}

// ---------------------------------------------------------------------------
// emb_gemm (fp32, unchanged from R6): embG = embpad @ W[2048:2248] + biases.
// ---------------------------------------------------------------------------
#define STEP(ACC, AV)                                  \
  ACC.x += AV.x * b0.x; ACC.y += AV.x * b0.y;          \
  ACC.x += AV.y * b1.x; ACC.y += AV.y * b1.y;          \
  ACC.x += AV.z * b2.x; ACC.y += AV.z * b2.y;          \
  ACC.x += AV.w * b3.x; ACC.y += AV.w * b3.y;

__device__ __forceinline__ void chunk_fma64(const float* __restrict__ Ab,
                                            const float* __restrict__ Bb,
                                            int l, float2* acc) {
  #pragma unroll
  for (int kq = 0; kq < 16; ++kq) {
    const float4 a0 = *(const float4*)(Ab + 0 * 64 + (kq << 2));
    const float4 a1 = *(const float4*)(Ab + 1 * 64 + (kq << 2));
    const float4 a2 = *(const float4*)(Ab + 2 * 64 + (kq << 2));
    const float4 a3 = *(const float4*)(Ab + 3 * 64 + (kq << 2));
    const float2 b0 = *(const float2*)(Bb + ((kq << 2) + 0) * 128 + (l << 1));
    const float2 b1 = *(const float2*)(Bb + ((kq << 2) + 1) * 128 + (l << 1));
    const float2 b2 = *(const float2*)(Bb + ((kq << 2) + 2) * 128 + (l << 1));
    const float2 b3 = *(const float2*)(Bb + ((kq << 2) + 3) * 128 + (l << 1));
    STEP(acc[0], a0) STEP(acc[1], a1) STEP(acc[2], a2) STEP(acc[3], a3)
  }
}

__global__ __launch_bounds__(512, 2) void emb_gemm(
    const float* __restrict__ Wpx, const float* __restrict__ Wix,
    const float* __restrict__ bpx, const float* __restrict__ bix,
    const float* __restrict__ bih) {
  __shared__ __align__(16) float smem[20480];
  const int tid = threadIdx.x, w = tid >> 6, l = tid & 63;
  const int mt = blockIdx.x / 48, ct = blockIdx.x % 48;
  const int c0 = ct << 7;
  const bool isproj = ct < 8;
  const float* W1 = isproj ? Wpx : Wix;
  const size_t N1 = isproj ? 1024 : 5120;
  const int c0x = isproj ? c0 : c0 - 1024;
  const int arow = (mt << 5) + (w << 2) + (l >> 4);
  const float* asrc = g_embpad + arow * 224 + ((l & 15) << 2);
  const int brow = (w << 3) + (l >> 5);
  const int bcol = (l & 31) << 2;

  auto STAGE = [&](int c, int buf) {
    float* base = smem + buf * 10240;
    const int kb = c << 6;
    gload_lds16(asrc + kb, base + (w << 8));
    #pragma unroll
    for (int j = 0; j < 4; ++j) {
      const int k = kb + brow + (j << 1);
      const float* srcB = (k < 200) ? (W1 + (size_t)(2048 + k) * N1 + c0x + bcol)
                                    : (g_zero + bcol);
      gload_lds16(srcB, base + 2048 + (((w << 3) + (j << 1)) << 7));
    }
  };

  float2 acc[4] = {{0.f,0.f},{0.f,0.f},{0.f,0.f},{0.f,0.f}};
  STAGE(0, 0);
  asm volatile("s_waitcnt vmcnt(0)" ::: "memory");
  __builtin_amdgcn_s_barrier();
  const int nch = 4;
  for (int c = 0; c < nch; ++c) {
    if (c + 1 < nch) STAGE(c + 1, (c + 1) & 1);
    const int cur = c & 1;
    chunk_fma64(smem + cur * 10240 + (w << 8), smem + cur * 10240 + 2048, l, acc);
    asm volatile("s_waitcnt vmcnt(0) lgkmcnt(0)" ::: "memory");
    __builtin_amdgcn_s_barrier();
  }
  const int cc = c0 + (l << 1);
  float2 bias;
  if (isproj) { bias.x = bpx[cc]; bias.y = bpx[cc + 1]; }
  else { bias.x = bix[cc - 1024] + bih[cc - 1024]; bias.y = bix[cc - 1023] + bih[cc - 1023]; }
  #pragma unroll
  for (int i = 0; i < 4; ++i) {
    const int r = (mt << 5) + (w << 2) + i;
    if (r < 152) {
      float2 o = { acc[i].x + bias.x, acc[i].y + bias.y };
      *(float2*)(g_embG + (size_t)r * 6144 + cc) = o;
    }
  }
}

// ---------------------------------------------------------------------------
// pre_gemm (MFMA): g_pre[m][c] = feat @ [Wpx|Wix], K=2048. 1536 blocks (32mtx48ct),
// 256 thr = 4 waves, wave = n-frag w. 2-deep register prefetch.
// ---------------------------------------------------------------------------
__global__ __launch_bounds__(256) void pre_gemm_mfma() {
  const int tid = threadIdx.x, w = tid >> 6, l = tid & 63;
  const int mt = blockIdx.x / 48, ct = blockIdx.x % 48;
  const int lk = l >> 5, lj = l & 31;
  const size_t abase = ((size_t)(mt * 256 + lk) * 32 + lj) * 8;
  const int nt = ct * 4 + w;
  const size_t bbase = ((size_t)(nt * 256 + lk) * 32 + lj) * 8;
  const short* pah = g_fpk_hi + abase;
  const short* pal = g_fpk_lo + abase;
  const short* pbh = g_Wpre_hi + bbase;
  const short* pbl = g_Wpre_lo + bbase;

  f32x16 acc = {};
  bf16x8 ah0 = *(const bf16x8*)pah,         al0 = *(const bf16x8*)pal;
  bf16x8 bh0 = *(const bf16x8*)pbh,         bl0 = *(const bf16x8*)pbl;
  bf16x8 ah1 = *(const bf16x8*)(pah + 512), al1 = *(const bf16x8*)(pal + 512);
  bf16x8 bh1 = *(const bf16x8*)(pbh + 512), bl1 = *(const bf16x8*)(pbl + 512);
  const int NS = 128;
  for (int s = 0; s + 2 < NS; ++s) {
    const size_t o = (size_t)(s + 2) * 512;
    bf16x8 ah2 = *(const bf16x8*)(pah + o), al2 = *(const bf16x8*)(pal + o);
    bf16x8 bh2 = *(const bf16x8*)(pbh + o), bl2 = *(const bf16x8*)(pbl + o);
    acc = mfma3(ah0, al0, bh0, bl0, acc);
    ah0 = ah1; al0 = al1; bh0 = bh1; bl0 = bl1;
    ah1 = ah2; al1 = al2; bh1 = bh2; bl1 = bl2;
  }
  acc = mfma3(ah0, al0, bh0, bl0, acc);
  acc = mfma3(ah1, al1, bh1, bl1, acc);

  const int colg = ct * 128 + w * 32 + lj;
  const int rb = mt * 32 + 4 * lk;
  #pragma unroll
  for (int reg = 0; reg < 16; ++reg) {
    const int r = rb + (reg & 3) + 8 * (reg >> 2);
    g_pre[(size_t)r * 6144 + colg] = acc[reg];
  }
}

// ---------------------------------------------------------------------------
// Main persistent kernel: per level, MFMA h-GEMM + phase B (gates/dist/commit,
// + child A-row packing).
// ---------------------------------------------------------------------------
__global__ __launch_bounds__(NTHR) void lstm_main(
    const int* __restrict__ parent,
    const float* __restrict__ Wout, const float* __restrict__ bout,
    float* __restrict__ out) {
  __shared__ float smem[1800];
  unsigned int gen = 0;
  const int tid = threadIdx.x;
  const int w = tid >> 6, l = tid & 63;
  const int lk = l >> 5, lj = l & 31;
  const int nl = g_numlvl;
  const int x = (int)blockIdx.x & 7, u = (int)blockIdx.x >> 3;  // u in [0,32)

  for (int L = 0; L < nl; ++L) {
    const int s0 = g_lvl_start[L];
    const int M  = g_lvl_start[L + 1] - s0;
    const int nmt = (M + 31) >> 5;
    const int toffL = g_tile_off[L];

    // -------- Phase A: g_gate = (ph @ Wih) + g_pre[:,1024:] + embG[er,1024:]
    for (int t = u; t < nmt * 5; t += 32) {
      const int mt = t / 5, cte = t - (t / 5) * 5;
      const int ct = x + (cte << 3);            // 0..39 (xcd-pinned)
      const int tg = toffL + mt;
      const size_t abase = ((size_t)(tg * 128 + lk) * 32 + lj) * 8;
      const int nt = ct * 4 + w;                // 0..159
      const size_t bbase = ((size_t)(nt * 128 + lk) * 32 + lj) * 8;
      const short* pah = g_Apk_hi + abase;
      const short* pal = g_Apk_lo + abase;
      const short* pbh = g_Wih_hi + bbase;
      const short* pbl = g_Wih_lo + bbase;

      f32x16 acc = {};
      bf16x8 ah0 = *(const bf16x8*)pah,         al0 = *(const bf16x8*)pal;
      bf16x8 bh0 = *(const bf16x8*)pbh,         bl0 = *(const bf16x8*)pbl;
      bf16x8 ah1 = *(const bf16x8*)(pah + 512), al1 = *(const bf16x8*)(pal + 512);
      bf16x8 bh1 = *(const bf16x8*)(pbh + 512), bl1 = *(const bf16x8*)(pbl + 512);
      const int NS = 64;
      for (int s = 0; s + 2 < NS; ++s) {
        const size_t o = (size_t)(s + 2) * 512;
        bf16x8 ah2 = *(const bf16x8*)(pah + o), al2 = *(const bf16x8*)(pal + o);
        bf16x8 bh2 = *(const bf16x8*)(pbh + o), bl2 = *(const bf16x8*)(pbl + o);
        acc = mfma3(ah0, al0, bh0, bl0, acc);
        ah0 = ah1; al0 = al1; bh0 = bh1; bl0 = bl1;
        ah1 = ah2; al1 = al2; bh1 = bh2; bl1 = bl2;
      }
      acc = mfma3(ah0, al0, bh0, bl0, acc);
      acc = mfma3(ah1, al1, bh1, bl1, acc);

      const int colg = ct * 128 + w * 32 + lj;  // 0..5119
      #pragma unroll
      for (int reg = 0; reg < 16; ++reg) {
        const int r = (reg & 3) + 8 * (reg >> 2) + 4 * lk;
        const int m = mt * 32 + r;
        if (m < M) {
          const int nd = g_order[s0 + m];
          const int pp = parent[nd];
          const int er = (pp < 0) ? 0 : g_commit[pp];
          const float v = acc[reg]
              + g_pre[(size_t)nd * 6144 + 1024 + colg]
              + g_embG[(size_t)er * 6144 + 1024 + colg];
          g_gate[(size_t)nd * 5120 + colg] = v;
        }
      }
    }
    gbar(&gen);

    // -------- Phase B --------
    for (int ni = (int)blockIdx.x; ni < M; ni += NBLK) {
      const int node = g_order[s0 + ni];
      const int p = parent[node];
      const int er = (p < 0) ? 0 : g_commit[p];
      const float* pre = g_pre + (size_t)node * 6144;
      const float* eg  = g_embG + (size_t)er * 6144;
      const float* gt  = g_gate + (size_t)node * 5120;
      const int cs = g_cstart[node], ce = g_cstart[node + 1];
      #pragma unroll
      for (int it = 0; it < 4; ++it) {
        const int j = (it << 8) + tid;
        const float proj = pre[j] + eg[j];
        const float vi = gt[j];
        const float vo = gt[1024 + j];
        const float vf = gt[2048 + j];
        const float vu = gt[3072 + j];
        const float vr = gt[4096 + j];
        const float ig = 1.f / (1.f + expf(-vi));
        const float og = 1.f / (1.f + expf(-vo));
        const float fg = 1.f / (1.f + expf(-vf));
        const float rg = 1.f / (1.f + expf(-vr));
        const float ug = tanhf(vu);
        const float pc = (p >= 0) ? g_c[(size_t)p * 1024 + j] : 0.f;
        const float c = ig * ug + fg * pc;
        const float h = og * tanhf(c);
        const float hf = rg * h + (1.f - rg) * proj;
        g_c[(size_t)node * 1024 + j] = c;
        smem[j] = hf;
        // pack hi/lo A rows for children
        unsigned short hh, hl;
        split2(hf, hh, hl);
        for (int ci = cs; ci < ce; ++ci) {
          const int pr = g_prow[g_clist[ci]];
          const size_t off = (((size_t)(pr >> 5) * 128 + (j >> 3)) * 32 + (pr & 31)) * 8 + (j & 7);
          g_Apk_hi[off] = (short)hh;
          g_Apk_lo[off] = (short)hl;
        }
      }
      __syncthreads();
      {
        const int kbeg = w << 8;   // 4 waves x 256 k
        for (int cb = 0; cb < 192; cb += 64) {
          const int col = cb + l;
          if (col < 151) {
            float a0 = 0.f, a1 = 0.f, a2 = 0.f, a3 = 0.f;
            float a4 = 0.f, a5 = 0.f, a6 = 0.f, a7 = 0.f;
            const float* wp = Wout + (size_t)kbeg * 151 + col;
            const float* hp = smem + kbeg;
            for (int kk = 0; kk < 256; kk += 8) {
              a0 += hp[kk + 0] * wp[(size_t)(kk + 0) * 151];
              a1 += hp[kk + 1] * wp[(size_t)(kk + 1) * 151];
              a2 += hp[kk + 2] * wp[(size_t)(kk + 2) * 151];
              a3 += hp[kk + 3] * wp[(size_t)(kk + 3) * 151];
              a4 += hp[kk + 4] * wp[(size_t)(kk + 4) * 151];
              a5 += hp[kk + 5] * wp[(size_t)(kk + 5) * 151];
              a6 += hp[kk + 6] * wp[(size_t)(kk + 6) * 151];
              a7 += hp[kk + 7] * wp[(size_t)(kk + 7) * 151];
            }
            smem[1024 + w * 152 + col] = ((a0 + a1) + (a2 + a3)) + ((a4 + a5) + (a6 + a7));
          }
        }
      }
      __syncthreads();
      if (tid < 151) {
        float d = bout[tid];
        #pragma unroll
        for (int ww = 0; ww < 4; ++ww) d += smem[1024 + ww * 152 + tid];
        smem[1632 + tid] = d;
        if (node >= 8) out[(size_t)(node - 8) * 151 + tid] = d;
      }
      __syncthreads();
      if (tid < 64) {
        float bv = -3.4e38f; int bidx = 1;
        for (int cb = 0; cb < 192; cb += 64) {
          const int col = 1 + cb + tid;
          if (col < 151) {
            const float v = smem[1632 + col];
            if (v > bv) { bv = v; bidx = col; }
          }
        }
        for (int off = 32; off > 0; off >>= 1) {
          const float ov = __shfl_down(bv, off);
          const int oi = __shfl_down(bidx, off);
          if (ov > bv || (ov == bv && oi < bidx)) { bv = ov; bidx = oi; }
        }
        if (tid == 0) {
          g_commit[node] = bidx;
          if (node >= 8) out[OUT_COMMIT_OFF + node - 8] = (float)bidx;
        }
      }
      __syncthreads();
    }
    gbar(&gen);
  }
}

extern "C" void kernel_launch(void* const* d_in, const int* in_sizes, int n_in,
                              void* d_out, int out_size, void* d_ws, size_t ws_size,
                              hipStream_t stream) {
  const float* feat   = (const float*)d_in[0];
  const int*   parent = (const int*)d_in[1];
  // d_in[2] = batch_size (8), hardcoded
  const float* Wpx  = (const float*)d_in[3];
  const float* bpx  = (const float*)d_in[4];
  const float* Wix  = (const float*)d_in[5];
  const float* bix  = (const float*)d_in[6];
  const float* Wih  = (const float*)d_in[7];
  const float* bih  = (const float*)d_in[8];
  const float* Wout = (const float*)d_in[9];
  const float* bout = (const float*)d_in[10];
  const float* emb  = (const float*)d_in[11];
  float* out = (float*)d_out;

  hipLaunchKernelGGL(prep_kernel, dim3(1), dim3(1024), 0, stream, parent, emb, out);
  hipLaunchKernelGGL(pack_all, dim3(2048), dim3(256), 0, stream, Wpx, Wix, Wih, feat);
  hipLaunchKernelGGL(emb_gemm, dim3(240), dim3(512), 0, stream, Wpx, Wix, bpx, bix, bih);
  hipLaunchKernelGGL(pre_gemm_mfma, dim3(1536), dim3(256), 0, stream);
  hipLaunchKernelGGL(lstm_main, dim3(NBLK), dim3(NTHR), 0, stream,
                     parent, Wout, bout, out);
}